// Round 7
// baseline (925.469 us; speedup 1.0000x reference)
//
#include <hip/hip_runtime.h>

#define NN 100000
#define NE 1600000
#define FEAT 128
#define NGRAPH 128
#define BSHIFT 9
#define NB 196          // ceil(NN / 512)
#define NCHUNK 400
#define CHUNK 4000      // NE / NCHUNK exactly

typedef __attribute__((ext_vector_type(8))) short bf16x8;
typedef __attribute__((ext_vector_type(4))) float f32x4;

__device__ __forceinline__ unsigned short f2bf(float f) {
    unsigned u = __float_as_uint(f);
    return (unsigned short)((u + 0x7fffu + ((u >> 16) & 1u)) >> 16);  // RNE
}
__device__ __forceinline__ float bf2f(unsigned short h) {
    return __uint_as_float(((unsigned)h) << 16);
}

// ==================== W hi/lo split prep ====================
__global__ __launch_bounds__(256)
void wsplit_kernel(const float* __restrict__ W, short* __restrict__ Wh,
                   short* __restrict__ Wl, int n)
{
    int i = blockIdx.x * 256 + threadIdx.x;
    if (i < n) {
        float f = W[i];
        unsigned short h = f2bf(f);
        Wh[i] = (short)h;
        Wl[i] = (short)f2bf(f - bf2f(h));
    }
}

// ==================== radix-partition CSR build ====================
__global__ __launch_bounds__(256)
void p1a_count(const int* __restrict__ ei, int* __restrict__ cnt_T)
{
    __shared__ int hist[NB];
    const int b = blockIdx.x, tid = threadIdx.x;
    for (int i = tid; i < NB; i += 256) hist[i] = 0;
    __syncthreads();
    const int e0 = b * CHUNK;
    for (int e = e0 + tid; e < e0 + CHUNK; e += 256)
        atomicAdd(&hist[ei[NE + e] >> BSHIFT], 1);
    __syncthreads();
    for (int k = tid; k < NB; k += 256) cnt_T[k * NCHUNK + b] = hist[k];
}

__global__ __launch_bounds__(1024)
void scan1_kernel(const int* __restrict__ in, int* __restrict__ out,
                  int* __restrict__ bsum, int n)
{
    __shared__ int sh[1024];
    const int tid = threadIdx.x;
    const int gid = blockIdx.x * 1024 + tid;
    int v = (gid < n) ? in[gid] : 0;
    sh[tid] = v;
    __syncthreads();
    #pragma unroll
    for (int d = 1; d < 1024; d <<= 1) {
        int t = (tid >= d) ? sh[tid - d] : 0;
        __syncthreads();
        sh[tid] += t;
        __syncthreads();
    }
    if (gid < n) out[gid] = sh[tid] - v;
    if (tid == 1023) bsum[blockIdx.x] = sh[1023];
}

__global__ __launch_bounds__(128)
void scan2_kernel(int* __restrict__ bsum, int nb)
{
    __shared__ int sh[128];
    const int tid = threadIdx.x;
    int v = (tid < nb) ? bsum[tid] : 0;
    sh[tid] = v;
    __syncthreads();
    #pragma unroll
    for (int d = 1; d < 128; d <<= 1) {
        int t = (tid >= d) ? sh[tid - d] : 0;
        __syncthreads();
        sh[tid] += t;
        __syncthreads();
    }
    if (tid < nb) bsum[tid] = sh[tid] - v;
}

__global__ __launch_bounds__(1024)
void scan3g_kernel(int* __restrict__ arr, const int* __restrict__ bsum, int n)
{
    const int gid = blockIdx.x * 1024 + threadIdx.x;
    if (gid < n) arr[gid] += bsum[blockIdx.x];
}

__global__ __launch_bounds__(256)
void p1b_scatter(const int* __restrict__ ei, const int* __restrict__ offs_T,
                 int2* __restrict__ ebuf)
{
    __shared__ int cur[NB];
    const int b = blockIdx.x, tid = threadIdx.x;
    for (int i = tid; i < NB; i += 256) cur[i] = offs_T[i * NCHUNK + b];
    __syncthreads();
    const int e0 = b * CHUNK;
    for (int e = e0 + tid; e < e0 + CHUNK; e += 256) {
        int s = ei[e], d = ei[NE + e];
        int pos = atomicAdd(&cur[d >> BSHIFT], 1);
        ebuf[pos] = make_int2(s, d);
    }
}

__global__ __launch_bounds__(512)
void p2_csr(const int2* __restrict__ ebuf, const int* __restrict__ offs_T,
            int* __restrict__ off, int* __restrict__ csr)
{
    __shared__ int degc[512];
    __shared__ int sh[512];
    const int k = blockIdx.x, tid = threadIdx.x;
    const int base = k << BSHIFT;
    const int bs = offs_T[k * NCHUNK];
    const int be = (k == NB - 1) ? NE : offs_T[(k + 1) * NCHUNK];
    degc[tid] = 0;
    __syncthreads();
    for (int e = bs + tid; e < be; e += 512)
        atomicAdd(&degc[ebuf[e].y - base], 1);
    __syncthreads();
    int v = degc[tid];
    sh[tid] = v;
    __syncthreads();
    #pragma unroll
    for (int d = 1; d < 512; d <<= 1) {
        int t = (tid >= d) ? sh[tid - d] : 0;
        __syncthreads();
        sh[tid] += t;
        __syncthreads();
    }
    const int excl = bs + sh[tid] - v;
    const int n = base + tid;
    if (n <= NN) off[n] = excl;
    degc[tid] = excl;
    __syncthreads();
    for (int e = bs + tid; e < be; e += 512) {
        int2 p = ebuf[e];
        int slot = atomicAdd(&degc[p.y - base], 1);
        csr[slot] = p.x;
    }
}

// ==================== aggregation: xeff = (h + sum_in h[src]) * 0.5 + h, split hi/lo ====================
__global__ __launch_bounds__(256)
void aggregate_split_kernel(const float* __restrict__ h, const int* __restrict__ off,
                            const int* __restrict__ csr, short* __restrict__ xH,
                            short* __restrict__ xL, int nn)
{
    const int node = blockIdx.x * 4 + (threadIdx.x >> 6);
    if (node >= nn) return;
    const int lane = threadIdx.x & 63;
    const int s = off[node], e = off[node + 1];
    float2 acc = make_float2(0.f, 0.f);
    for (int base = s; base < e; base += 64) {
        const int cnt = min(64, e - base);
        int src_l = (base + lane < e) ? csr[base + lane] : 0;
        int j = 0;
        for (; j + 4 <= cnt; j += 4) {
            int s0 = __shfl(src_l, j + 0);
            int s1 = __shfl(src_l, j + 1);
            int s2 = __shfl(src_l, j + 2);
            int s3 = __shfl(src_l, j + 3);
            float2 v0 = reinterpret_cast<const float2*>(h + (size_t)s0 * FEAT)[lane];
            float2 v1 = reinterpret_cast<const float2*>(h + (size_t)s1 * FEAT)[lane];
            float2 v2 = reinterpret_cast<const float2*>(h + (size_t)s2 * FEAT)[lane];
            float2 v3 = reinterpret_cast<const float2*>(h + (size_t)s3 * FEAT)[lane];
            acc.x += v0.x + v1.x + v2.x + v3.x;
            acc.y += v0.y + v1.y + v2.y + v3.y;
        }
        for (; j < cnt; ++j) {
            int sj = __shfl(src_l, j);
            float2 v = reinterpret_cast<const float2*>(h + (size_t)sj * FEAT)[lane];
            acc.x += v.x; acc.y += v.y;
        }
    }
    float2 hv = reinterpret_cast<const float2*>(h + (size_t)node * FEAT)[lane];
    float ox = (hv.x + acc.x) * 0.5f + hv.x;
    float oy = (hv.y + acc.y) * 0.5f + hv.y;
    unsigned short hx = f2bf(ox), hy = f2bf(oy);
    short2 hi2 = make_short2((short)hx, (short)hy);
    short2 lo2 = make_short2((short)f2bf(ox - bf2f(hx)), (short)f2bf(oy - bf2f(hy)));
    reinterpret_cast<short2*>(xH + (size_t)node * FEAT)[lane] = hi2;
    reinterpret_cast<short2*>(xL + (size_t)node * FEAT)[lane] = lo2;
}

// ==================== MFMA split-bf16 GEMM v2: no LDS, A-frags direct from planes ====================
// C = Ah*Wh + Al*Wh + Ah*Wl. Block: 4 waves x 32 rows = 128 rows, all 128 cols per wave.
// Output: fp32 (outF) or split planes (outH/outL), relu applied.
__global__ __launch_bounds__(256)
void gemm_mfma2_kernel(const short* __restrict__ aH, const short* __restrict__ aL,
                       const short* __restrict__ Wh, const short* __restrict__ Wl,
                       const float* __restrict__ bias,
                       float* __restrict__ outF, short* __restrict__ outH,
                       short* __restrict__ outL, int n_nodes)
{
    const int tid = threadIdx.x;
    const int lane = tid & 63;
    const int w = tid >> 6;
    const int lr = lane & 15;
    const int lk = (lane >> 4) << 3;                 // 0,8,16,24
    const int row0 = blockIdx.x * 128 + w * 32;

    // preload all A fragments (hidden under the MFMA run)
    bf16x8 ah[4][2], al[4][2];
    #pragma unroll
    for (int rt = 0; rt < 2; ++rt) {
        const int row = row0 + rt * 16 + lr;
        if (row < n_nodes) {
            const size_t rb = (size_t)row * FEAT;
            #pragma unroll
            for (int kc = 0; kc < 4; ++kc) {
                ah[kc][rt] = *reinterpret_cast<const bf16x8*>(&aH[rb + kc * 32 + lk]);
                al[kc][rt] = *reinterpret_cast<const bf16x8*>(&aL[rb + kc * 32 + lk]);
            }
        } else {
            bf16x8 z = {};
            #pragma unroll
            for (int kc = 0; kc < 4; ++kc) { ah[kc][rt] = z; al[kc][rt] = z; }
        }
    }

    f32x4 acc[2][8] = {};
    #pragma unroll
    for (int kc = 0; kc < 4; ++kc) {
        const int kf = kc * 32 + lk;
        #pragma unroll
        for (int ct = 0; ct < 8; ++ct) {
            const int o = ct * 16 + lr;
            bf16x8 bh = *reinterpret_cast<const bf16x8*>(&Wh[o * FEAT + kf]);
            bf16x8 bl = *reinterpret_cast<const bf16x8*>(&Wl[o * FEAT + kf]);
            #pragma unroll
            for (int rt = 0; rt < 2; ++rt) {
                acc[rt][ct] = __builtin_amdgcn_mfma_f32_16x16x32_bf16(ah[kc][rt], bh, acc[rt][ct], 0, 0, 0);
                acc[rt][ct] = __builtin_amdgcn_mfma_f32_16x16x32_bf16(al[kc][rt], bh, acc[rt][ct], 0, 0, 0);
                acc[rt][ct] = __builtin_amdgcn_mfma_f32_16x16x32_bf16(ah[kc][rt], bl, acc[rt][ct], 0, 0, 0);
            }
        }
    }

    // epilogue: C col = lane&15, row = (lane>>4)*4 + j
    #pragma unroll
    for (int rt = 0; rt < 2; ++rt) {
        const int rbase = row0 + rt * 16 + ((lane >> 4) << 2);
        #pragma unroll
        for (int ct = 0; ct < 8; ++ct) {
            const int col = ct * 16 + lr;
            const float b = bias[col];
            #pragma unroll
            for (int j = 0; j < 4; ++j) {
                const int n = rbase + j;
                if (n < n_nodes) {
                    float v = fmaxf(acc[rt][ct][j] + b, 0.f);
                    if (outF) {
                        outF[(size_t)n * FEAT + col] = v;
                    } else {
                        unsigned short hh = f2bf(v);
                        outH[(size_t)n * FEAT + col] = (short)hh;
                        outL[(size_t)n * FEAT + col] = (short)f2bf(v - bf2f(hh));
                    }
                }
            }
        }
    }
}

// ==================== pooling ====================
__global__ __launch_bounds__(512)
void pool_kernel(const float* __restrict__ y, const int* __restrict__ batch,
                 float* __restrict__ out, int n_nodes, int layer)
{
    const int g = blockIdx.x;
    int lo = 0, hi = n_nodes;
    while (lo < hi) { int mid = (lo + hi) >> 1; if (batch[mid] < g) lo = mid + 1; else hi = mid; }
    const int start = lo;
    hi = n_nodes;
    while (lo < hi) { int mid = (lo + hi) >> 1; if (batch[mid] < g + 1) lo = mid + 1; else hi = mid; }
    const int end = lo;

    const int tid = threadIdx.x;
    const int f = tid & 127;
    const int q = tid >> 7;
    float sum = 0.f;
    for (int n = start + q; n < end; n += 4)
        sum += y[(size_t)n * FEAT + f];

    __shared__ float red[512];
    red[tid] = sum;
    __syncthreads();
    if (tid < 128)
        out[g * (3 * FEAT) + layer * FEAT + tid]
            = red[tid] + red[tid + 128] + red[tid + 256] + red[tid + 384];
}

// ==================== fallback path kernels (ws too small) ====================
__global__ __launch_bounds__(256)
void scatter_kernel(const float* __restrict__ h, const int* __restrict__ ei,
                    float* __restrict__ agg, int n_edges)
{
    int e = blockIdx.x * 4 + (threadIdx.x >> 6);
    if (e >= n_edges) return;
    int lane = threadIdx.x & 63;
    int s = ei[e];
    int d = ei[n_edges + e];
    float2 v = reinterpret_cast<const float2*>(h + (size_t)s * FEAT)[lane];
    float* ap = agg + (size_t)d * FEAT + lane * 2;
    atomicAdd(ap, v.x);
    atomicAdd(ap + 1, v.y);
}

__global__ __launch_bounds__(256)
void combine_kernel(const float* __restrict__ h, float* __restrict__ agg_xeff, size_t n4)
{
    size_t i = (size_t)blockIdx.x * 256 + threadIdx.x;
    if (i >= n4) return;
    float4 a = reinterpret_cast<const float4*>(h)[i];
    float4 g = reinterpret_cast<float4*>(agg_xeff)[i];
    float4 o;
    o.x = (a.x + g.x) * 0.5f + a.x;
    o.y = (a.y + g.y) * 0.5f + a.y;
    o.z = (a.z + g.z) * 0.5f + a.z;
    o.w = (a.w + g.w) * 0.5f + a.w;
    reinterpret_cast<float4*>(agg_xeff)[i] = o;
}

__global__ __launch_bounds__(256, 2)
void gemm_relu_kernel(const float* __restrict__ A, const float* __restrict__ W,
                      const float* __restrict__ bias, float* __restrict__ out, int n_nodes)
{
    __shared__ float xt[64][128];
    __shared__ float wt[64][128];
    const int tid = threadIdx.x;
    const int row0 = blockIdx.x * 128;
    const int r  = tid >> 1;
    const int ks = (tid & 1) << 5;
    const int tn = (tid >> 4) << 3;
    const int to = (tid & 15) << 3;
    float acc[8][8] = {};

    for (int c = 0; c < 2; ++c) {
        const int k0 = c * 64;
        {
            const float4* wrow = reinterpret_cast<const float4*>(W + r * FEAT + k0 + ks);
            #pragma unroll
            for (int i = 0; i < 8; ++i) {
                float4 w4 = wrow[i];
                int kk = ks + i * 4;
                wt[kk + 0][r] = w4.x; wt[kk + 1][r] = w4.y;
                wt[kk + 2][r] = w4.z; wt[kk + 3][r] = w4.w;
            }
        }
        {
            const int n = row0 + r;
            if (n < n_nodes) {
                const float4* ar = reinterpret_cast<const float4*>(A + (size_t)n * FEAT + k0 + ks);
                #pragma unroll
                for (int i = 0; i < 8; ++i) {
                    float4 a4 = ar[i];
                    int kk = ks + i * 4;
                    xt[kk + 0][r] = a4.x; xt[kk + 1][r] = a4.y;
                    xt[kk + 2][r] = a4.z; xt[kk + 3][r] = a4.w;
                }
            } else {
                #pragma unroll
                for (int i = 0; i < 8; ++i) {
                    int kk = ks + i * 4;
                    xt[kk + 0][r] = 0.f; xt[kk + 1][r] = 0.f;
                    xt[kk + 2][r] = 0.f; xt[kk + 3][r] = 0.f;
                }
            }
        }
        __syncthreads();
        #pragma unroll 4
        for (int k = 0; k < 64; ++k) {
            float4 x0 = *reinterpret_cast<const float4*>(&xt[k][tn]);
            float4 x1 = *reinterpret_cast<const float4*>(&xt[k][tn + 4]);
            float4 w0 = *reinterpret_cast<const float4*>(&wt[k][to]);
            float4 w1 = *reinterpret_cast<const float4*>(&wt[k][to + 4]);
            float xv[8] = {x0.x, x0.y, x0.z, x0.w, x1.x, x1.y, x1.z, x1.w};
            float wv[8] = {w0.x, w0.y, w0.z, w0.w, w1.x, w1.y, w1.z, w1.w};
            #pragma unroll
            for (int i = 0; i < 8; ++i)
                #pragma unroll
                for (int j = 0; j < 8; ++j)
                    acc[i][j] = fmaf(xv[i], wv[j], acc[i][j]);
        }
        __syncthreads();
    }

    float bv[8];
    #pragma unroll
    for (int j = 0; j < 8; ++j) bv[j] = bias[to + j];
    #pragma unroll
    for (int i = 0; i < 8; ++i) {
        int n = row0 + tn + i;
        if (n >= n_nodes) break;
        float4 o0, o1;
        o0.x = fmaxf(acc[i][0] + bv[0], 0.f);
        o0.y = fmaxf(acc[i][1] + bv[1], 0.f);
        o0.z = fmaxf(acc[i][2] + bv[2], 0.f);
        o0.w = fmaxf(acc[i][3] + bv[3], 0.f);
        o1.x = fmaxf(acc[i][4] + bv[4], 0.f);
        o1.y = fmaxf(acc[i][5] + bv[5], 0.f);
        o1.z = fmaxf(acc[i][6] + bv[6], 0.f);
        o1.w = fmaxf(acc[i][7] + bv[7], 0.f);
        float* op = out + (size_t)n * FEAT + to;
        *reinterpret_cast<float4*>(op) = o0;
        *reinterpret_cast<float4*>(op + 4) = o1;
    }
}

extern "C" void kernel_launch(void* const* d_in, const int* in_sizes, int n_in,
                              void* d_out, int out_size, void* d_ws, size_t ws_size,
                              hipStream_t stream)
{
    const float* x     = (const float*)d_in[0];
    const int*   ei    = (const int*)d_in[1];
    const int*   batch = (const int*)d_in[2];
    const float* W1[3] = {(const float*)d_in[4], (const float*)d_in[8],  (const float*)d_in[12]};
    const float* b1[3] = {(const float*)d_in[5], (const float*)d_in[9],  (const float*)d_in[13]};
    const float* W2[3] = {(const float*)d_in[6], (const float*)d_in[10], (const float*)d_in[14]};
    const float* b2[3] = {(const float*)d_in[7], (const float*)d_in[11], (const float*)d_in[15]};

    const size_t nf = (size_t)NN * FEAT;
    float* outp = (float*)d_out;
    const int gemm_grid = (NN + 127) / 128;
    const int M = NB * NCHUNK;                       // 78400
    const int scanM_blocks = (M + 1023) / 1024;      // 77
    const int WN = FEAT * FEAT;                      // 16384

    const size_t need_full = 3 * nf * 4 + (size_t)(NN + 1 + NE) * 4 + (size_t)12 * WN * 2;

    if (ws_size >= need_full) {
        short* xeffH = (short*)d_ws;           // nf shorts
        short* xeffL = xeffH + nf;             // nf shorts
        short* h1H   = xeffL + nf;             // nf shorts
        short* h1L   = h1H + nf;               // nf shorts
        float* bufC  = (float*)(h1L + nf);     // nf floats
        int* off     = (int*)(bufC + nf);      // NN+1
        int* csr     = off + (NN + 1);         // NE
        short* wbase = (short*)(csr + NE);     // 12 * WN shorts
        short* wh[6], * wl[6];
        for (int i = 0; i < 6; ++i) { wh[i] = wbase + i * WN; wl[i] = wbase + (6 + i) * WN; }
        // build transients aliased into plane space (written only after build)
        int* cnt_T  = (int*)xeffH;             // M
        int* offs_T = cnt_T + M;               // M
        int* bsum   = offs_T + M;              // 77
        int2* ebuf  = (int2*)h1H;              // NE pairs (12.8 MB)

        const float* Ws[6] = {W1[0], W2[0], W1[1], W2[1], W1[2], W2[2]};
        for (int i = 0; i < 6; ++i)
            wsplit_kernel<<<(WN + 255) / 256, 256, 0, stream>>>(Ws[i], wh[i], wl[i], WN);

        p1a_count<<<NCHUNK, 256, 0, stream>>>(ei, cnt_T);
        scan1_kernel<<<scanM_blocks, 1024, 0, stream>>>(cnt_T, offs_T, bsum, M);
        scan2_kernel<<<1, 128, 0, stream>>>(bsum, scanM_blocks);
        scan3g_kernel<<<scanM_blocks, 1024, 0, stream>>>(offs_T, bsum, M);
        p1b_scatter<<<NCHUNK, 256, 0, stream>>>(ei, offs_T, ebuf);
        p2_csr<<<NB, 512, 0, stream>>>(ebuf, offs_T, off, csr);

        const float* h = x;
        for (int l = 0; l < 3; ++l) {
            aggregate_split_kernel<<<(NN + 3) / 4, 256, 0, stream>>>(h, off, csr, xeffH, xeffL, NN);
            gemm_mfma2_kernel<<<gemm_grid, 256, 0, stream>>>(xeffH, xeffL, wh[2 * l], wl[2 * l],
                                                             b1[l], nullptr, h1H, h1L, NN);
            gemm_mfma2_kernel<<<gemm_grid, 256, 0, stream>>>(h1H, h1L, wh[2 * l + 1], wl[2 * l + 1],
                                                             b2[l], bufC, nullptr, nullptr, NN);
            pool_kernel<<<NGRAPH, 512, 0, stream>>>(bufC, batch, outp, NN, l);
            h = bufC;
        }
    } else if (ws_size >= 3 * nf * 4) {
        float* bufA = (float*)d_ws;
        float* bufB = bufA + nf;
        float* bufC = bufB + nf;
        const float* h = x;
        for (int l = 0; l < 3; ++l) {
            hipMemsetAsync(bufA, 0, nf * 4, stream);
            scatter_kernel<<<(NE + 3) / 4, 256, 0, stream>>>(h, ei, bufA, NE);
            combine_kernel<<<(int)((nf / 4 + 255) / 256), 256, 0, stream>>>(h, bufA, nf / 4);
            gemm_relu_kernel<<<gemm_grid, 256, 0, stream>>>(bufA, W1[l], b1[l], bufB, NN);
            gemm_relu_kernel<<<gemm_grid, 256, 0, stream>>>(bufB, W2[l], b2[l], bufC, NN);
            pool_kernel<<<NGRAPH, 512, 0, stream>>>(bufC, batch, outp, NN, l);
            h = bufC;
        }
    }
}

// Round 8
// 791.042 us; speedup vs baseline: 1.1699x; 1.1699x over previous
//
#include <hip/hip_runtime.h>

#define NN 100000
#define NE 1600000
#define FEAT 128
#define NGRAPH 128
#define BSHIFT 9
#define NB 196          // ceil(NN / 512)
#define NCHUNK 400
#define CHUNK 4000      // NE / NCHUNK exactly

typedef __attribute__((ext_vector_type(8))) short bf16x8;
typedef __attribute__((ext_vector_type(4))) float f32x4;

__device__ __forceinline__ unsigned short f2bf(float f) {
    unsigned u = __float_as_uint(f);
    return (unsigned short)((u + 0x7fffu + ((u >> 16) & 1u)) >> 16);  // RNE
}
__device__ __forceinline__ float bf2f(unsigned short h) {
    return __uint_as_float(((unsigned)h) << 16);
}

// ==================== W hi/lo split -> fragment-major layout ====================
// Layout (shorts): plane p in {0=hi,1=lo}: idx = p*16384 + (kc*8+ct)*512 + lane*8 + j
// where for element W[o][k]: ct=o>>4, lr=o&15, kc=k>>5, q=(k>>3)&3, j=k&7, lane=q*16+lr.
// Per (kc,ct) MFMA fragment read: lane l reads 16B at chunk l -> fully lane-consecutive.
__global__ __launch_bounds__(256)
void wsplit_frag_kernel(const float* __restrict__ W, short* __restrict__ Wf)
{
    int i = blockIdx.x * 256 + threadIdx.x;   // 16384 elements
    int o = i >> 7, k = i & 127;
    float f = W[i];
    unsigned short h = f2bf(f);
    short lo = (short)f2bf(f - bf2f(h));
    int ct = o >> 4, lr = o & 15, kc = k >> 5, q = (k >> 3) & 3, j = k & 7;
    int idx = (kc * 8 + ct) * 512 + ((q << 4) | lr) * 8 + j;
    Wf[idx] = (short)h;
    Wf[16384 + idx] = lo;
}

// ==================== radix-partition CSR build ====================
__global__ __launch_bounds__(256)
void p1a_count(const int* __restrict__ ei, int* __restrict__ cnt_T)
{
    __shared__ int hist[NB];
    const int b = blockIdx.x, tid = threadIdx.x;
    for (int i = tid; i < NB; i += 256) hist[i] = 0;
    __syncthreads();
    const int e0 = b * CHUNK;
    for (int e = e0 + tid; e < e0 + CHUNK; e += 256)
        atomicAdd(&hist[ei[NE + e] >> BSHIFT], 1);
    __syncthreads();
    for (int k = tid; k < NB; k += 256) cnt_T[k * NCHUNK + b] = hist[k];
}

__global__ __launch_bounds__(1024)
void scan1_kernel(const int* __restrict__ in, int* __restrict__ out,
                  int* __restrict__ bsum, int n)
{
    __shared__ int sh[1024];
    const int tid = threadIdx.x;
    const int gid = blockIdx.x * 1024 + tid;
    int v = (gid < n) ? in[gid] : 0;
    sh[tid] = v;
    __syncthreads();
    #pragma unroll
    for (int d = 1; d < 1024; d <<= 1) {
        int t = (tid >= d) ? sh[tid - d] : 0;
        __syncthreads();
        sh[tid] += t;
        __syncthreads();
    }
    if (gid < n) out[gid] = sh[tid] - v;
    if (tid == 1023) bsum[blockIdx.x] = sh[1023];
}

__global__ __launch_bounds__(128)
void scan2_kernel(int* __restrict__ bsum, int nb)
{
    __shared__ int sh[128];
    const int tid = threadIdx.x;
    int v = (tid < nb) ? bsum[tid] : 0;
    sh[tid] = v;
    __syncthreads();
    #pragma unroll
    for (int d = 1; d < 128; d <<= 1) {
        int t = (tid >= d) ? sh[tid - d] : 0;
        __syncthreads();
        sh[tid] += t;
        __syncthreads();
    }
    if (tid < nb) bsum[tid] = sh[tid] - v;
}

__global__ __launch_bounds__(1024)
void scan3g_kernel(int* __restrict__ arr, const int* __restrict__ bsum, int n)
{
    const int gid = blockIdx.x * 1024 + threadIdx.x;
    if (gid < n) arr[gid] += bsum[blockIdx.x];
}

__global__ __launch_bounds__(256)
void p1b_scatter(const int* __restrict__ ei, const int* __restrict__ offs_T,
                 int2* __restrict__ ebuf)
{
    __shared__ int cur[NB];
    const int b = blockIdx.x, tid = threadIdx.x;
    for (int i = tid; i < NB; i += 256) cur[i] = offs_T[i * NCHUNK + b];
    __syncthreads();
    const int e0 = b * CHUNK;
    for (int e = e0 + tid; e < e0 + CHUNK; e += 256) {
        int s = ei[e], d = ei[NE + e];
        int pos = atomicAdd(&cur[d >> BSHIFT], 1);
        ebuf[pos] = make_int2(s, d);
    }
}

__global__ __launch_bounds__(512)
void p2_csr(const int2* __restrict__ ebuf, const int* __restrict__ offs_T,
            int* __restrict__ off, int* __restrict__ csr)
{
    __shared__ int degc[512];
    __shared__ int sh[512];
    const int k = blockIdx.x, tid = threadIdx.x;
    const int base = k << BSHIFT;
    const int bs = offs_T[k * NCHUNK];
    const int be = (k == NB - 1) ? NE : offs_T[(k + 1) * NCHUNK];
    degc[tid] = 0;
    __syncthreads();
    for (int e = bs + tid; e < be; e += 512)
        atomicAdd(&degc[ebuf[e].y - base], 1);
    __syncthreads();
    int v = degc[tid];
    sh[tid] = v;
    __syncthreads();
    #pragma unroll
    for (int d = 1; d < 512; d <<= 1) {
        int t = (tid >= d) ? sh[tid - d] : 0;
        __syncthreads();
        sh[tid] += t;
        __syncthreads();
    }
    const int excl = bs + sh[tid] - v;
    const int n = base + tid;
    if (n <= NN) off[n] = excl;
    degc[tid] = excl;
    __syncthreads();
    for (int e = bs + tid; e < be; e += 512) {
        int2 p = ebuf[e];
        int slot = atomicAdd(&degc[p.y - base], 1);
        csr[slot] = p.x;
    }
}

// ==================== aggregation: xeff = (h + sum_in h[src]) * 0.5 + h, split hi/lo ====================
__global__ __launch_bounds__(256)
void aggregate_split_kernel(const float* __restrict__ h, const int* __restrict__ off,
                            const int* __restrict__ csr, short* __restrict__ xH,
                            short* __restrict__ xL, int nn)
{
    const int node = blockIdx.x * 4 + (threadIdx.x >> 6);
    if (node >= nn) return;
    const int lane = threadIdx.x & 63;
    const int s = off[node], e = off[node + 1];
    float2 acc = make_float2(0.f, 0.f);
    for (int base = s; base < e; base += 64) {
        const int cnt = min(64, e - base);
        int src_l = (base + lane < e) ? csr[base + lane] : 0;
        int j = 0;
        for (; j + 4 <= cnt; j += 4) {
            int s0 = __shfl(src_l, j + 0);
            int s1 = __shfl(src_l, j + 1);
            int s2 = __shfl(src_l, j + 2);
            int s3 = __shfl(src_l, j + 3);
            float2 v0 = reinterpret_cast<const float2*>(h + (size_t)s0 * FEAT)[lane];
            float2 v1 = reinterpret_cast<const float2*>(h + (size_t)s1 * FEAT)[lane];
            float2 v2 = reinterpret_cast<const float2*>(h + (size_t)s2 * FEAT)[lane];
            float2 v3 = reinterpret_cast<const float2*>(h + (size_t)s3 * FEAT)[lane];
            acc.x += v0.x + v1.x + v2.x + v3.x;
            acc.y += v0.y + v1.y + v2.y + v3.y;
        }
        for (; j < cnt; ++j) {
            int sj = __shfl(src_l, j);
            float2 v = reinterpret_cast<const float2*>(h + (size_t)sj * FEAT)[lane];
            acc.x += v.x; acc.y += v.y;
        }
    }
    float2 hv = reinterpret_cast<const float2*>(h + (size_t)node * FEAT)[lane];
    float ox = (hv.x + acc.x) * 0.5f + hv.x;
    float oy = (hv.y + acc.y) * 0.5f + hv.y;
    unsigned short hx = f2bf(ox), hy = f2bf(oy);
    short2 hi2 = make_short2((short)hx, (short)hy);
    short2 lo2 = make_short2((short)f2bf(ox - bf2f(hx)), (short)f2bf(oy - bf2f(hy)));
    reinterpret_cast<short2*>(xH + (size_t)node * FEAT)[lane] = hi2;
    reinterpret_cast<short2*>(xL + (size_t)node * FEAT)[lane] = lo2;
}

// ==================== MFMA split-bf16 GEMM v3: W in LDS (frag-major), A in regs ====================
// C = Ah*Wh + Al*Wh + Ah*Wl. Block: 512 threads = 8 waves x 32 rows = 256 rows.
__global__ __launch_bounds__(512)
void gemm_mfma3_kernel(const short* __restrict__ aH, const short* __restrict__ aL,
                       const short* __restrict__ Wf, const float* __restrict__ bias,
                       float* __restrict__ outF, short* __restrict__ outH,
                       short* __restrict__ outL, int n_nodes)
{
    __shared__ short wlds[32768];   // 64 KB: [hi|lo] frag-major
    const int tid = threadIdx.x;
    const int lane = tid & 63;
    const int w = tid >> 6;
    const int lr = lane & 15;
    const int lk = (lane >> 4) << 3;
    const int row0 = blockIdx.x * 256 + w * 32;

    // stage W: straight 64KB copy, lane-consecutive 16B chunks
    {
        const bf16x8* src = reinterpret_cast<const bf16x8*>(Wf);
        bf16x8* dst = reinterpret_cast<bf16x8*>(wlds);
        #pragma unroll
        for (int it = 0; it < 8; ++it)
            dst[it * 512 + tid] = src[it * 512 + tid];
    }

    // preload A fragments to registers (streaming; hidden under MFMA run)
    const int r0 = row0 + lr;
    const int r1 = row0 + 16 + lr;
    const size_t rb0 = (size_t)r0 * FEAT + lk;
    const size_t rb1 = (size_t)r1 * FEAT + lk;
    const bool v0 = (r0 < n_nodes), v1 = (r1 < n_nodes);
    bf16x8 z = {};
    bf16x8 ah[4][2], al[4][2];
    #pragma unroll
    for (int kc = 0; kc < 4; ++kc) {
        ah[kc][0] = v0 ? *reinterpret_cast<const bf16x8*>(&aH[rb0 + kc * 32]) : z;
        al[kc][0] = v0 ? *reinterpret_cast<const bf16x8*>(&aL[rb0 + kc * 32]) : z;
        ah[kc][1] = v1 ? *reinterpret_cast<const bf16x8*>(&aH[rb1 + kc * 32]) : z;
        al[kc][1] = v1 ? *reinterpret_cast<const bf16x8*>(&aL[rb1 + kc * 32]) : z;
    }
    __syncthreads();

    f32x4 acc[2][8] = {};
    #pragma unroll
    for (int kc = 0; kc < 4; ++kc) {
        #pragma unroll
        for (int ct = 0; ct < 8; ++ct) {
            const int ra = (kc * 8 + ct) * 512 + lane * 8;
            bf16x8 bh = *reinterpret_cast<const bf16x8*>(&wlds[ra]);
            bf16x8 bl = *reinterpret_cast<const bf16x8*>(&wlds[16384 + ra]);
            #pragma unroll
            for (int rt = 0; rt < 2; ++rt) {
                acc[rt][ct] = __builtin_amdgcn_mfma_f32_16x16x32_bf16(ah[kc][rt], bh, acc[rt][ct], 0, 0, 0);
                acc[rt][ct] = __builtin_amdgcn_mfma_f32_16x16x32_bf16(al[kc][rt], bh, acc[rt][ct], 0, 0, 0);
                acc[rt][ct] = __builtin_amdgcn_mfma_f32_16x16x32_bf16(ah[kc][rt], bl, acc[rt][ct], 0, 0, 0);
            }
        }
    }

    // epilogue: C col = lane&15, row = (lane>>4)*4 + j
    #pragma unroll
    for (int rt = 0; rt < 2; ++rt) {
        const int rbase = row0 + rt * 16 + ((lane >> 4) << 2);
        #pragma unroll
        for (int ct = 0; ct < 8; ++ct) {
            const int col = ct * 16 + lr;
            const float b = bias[col];
            #pragma unroll
            for (int j = 0; j < 4; ++j) {
                const int n = rbase + j;
                if (n < n_nodes) {
                    float v = fmaxf(acc[rt][ct][j] + b, 0.f);
                    if (outF) {
                        outF[(size_t)n * FEAT + col] = v;
                    } else {
                        unsigned short hh = f2bf(v);
                        outH[(size_t)n * FEAT + col] = (short)hh;
                        outL[(size_t)n * FEAT + col] = (short)f2bf(v - bf2f(hh));
                    }
                }
            }
        }
    }
}

// ==================== pooling ====================
__global__ __launch_bounds__(512)
void pool_kernel(const float* __restrict__ y, const int* __restrict__ batch,
                 float* __restrict__ out, int n_nodes, int layer)
{
    const int g = blockIdx.x;
    int lo = 0, hi = n_nodes;
    while (lo < hi) { int mid = (lo + hi) >> 1; if (batch[mid] < g) lo = mid + 1; else hi = mid; }
    const int start = lo;
    hi = n_nodes;
    while (lo < hi) { int mid = (lo + hi) >> 1; if (batch[mid] < g + 1) lo = mid + 1; else hi = mid; }
    const int end = lo;

    const int tid = threadIdx.x;
    const int f = tid & 127;
    const int q = tid >> 7;
    float sum = 0.f;
    for (int n = start + q; n < end; n += 4)
        sum += y[(size_t)n * FEAT + f];

    __shared__ float red[512];
    red[tid] = sum;
    __syncthreads();
    if (tid < 128)
        out[g * (3 * FEAT) + layer * FEAT + tid]
            = red[tid] + red[tid + 128] + red[tid + 256] + red[tid + 384];
}

// ==================== fallback path kernels (ws too small) ====================
__global__ __launch_bounds__(256)
void scatter_kernel(const float* __restrict__ h, const int* __restrict__ ei,
                    float* __restrict__ agg, int n_edges)
{
    int e = blockIdx.x * 4 + (threadIdx.x >> 6);
    if (e >= n_edges) return;
    int lane = threadIdx.x & 63;
    int s = ei[e];
    int d = ei[n_edges + e];
    float2 v = reinterpret_cast<const float2*>(h + (size_t)s * FEAT)[lane];
    float* ap = agg + (size_t)d * FEAT + lane * 2;
    atomicAdd(ap, v.x);
    atomicAdd(ap + 1, v.y);
}

__global__ __launch_bounds__(256)
void combine_kernel(const float* __restrict__ h, float* __restrict__ agg_xeff, size_t n4)
{
    size_t i = (size_t)blockIdx.x * 256 + threadIdx.x;
    if (i >= n4) return;
    float4 a = reinterpret_cast<const float4*>(h)[i];
    float4 g = reinterpret_cast<float4*>(agg_xeff)[i];
    float4 o;
    o.x = (a.x + g.x) * 0.5f + a.x;
    o.y = (a.y + g.y) * 0.5f + a.y;
    o.z = (a.z + g.z) * 0.5f + a.z;
    o.w = (a.w + g.w) * 0.5f + a.w;
    reinterpret_cast<float4*>(agg_xeff)[i] = o;
}

__global__ __launch_bounds__(256, 2)
void gemm_relu_kernel(const float* __restrict__ A, const float* __restrict__ W,
                      const float* __restrict__ bias, float* __restrict__ out, int n_nodes)
{
    __shared__ float xt[64][128];
    __shared__ float wt[64][128];
    const int tid = threadIdx.x;
    const int row0 = blockIdx.x * 128;
    const int r  = tid >> 1;
    const int ks = (tid & 1) << 5;
    const int tn = (tid >> 4) << 3;
    const int to = (tid & 15) << 3;
    float acc[8][8] = {};

    for (int c = 0; c < 2; ++c) {
        const int k0 = c * 64;
        {
            const float4* wrow = reinterpret_cast<const float4*>(W + r * FEAT + k0 + ks);
            #pragma unroll
            for (int i = 0; i < 8; ++i) {
                float4 w4 = wrow[i];
                int kk = ks + i * 4;
                wt[kk + 0][r] = w4.x; wt[kk + 1][r] = w4.y;
                wt[kk + 2][r] = w4.z; wt[kk + 3][r] = w4.w;
            }
        }
        {
            const int n = row0 + r;
            if (n < n_nodes) {
                const float4* ar = reinterpret_cast<const float4*>(A + (size_t)n * FEAT + k0 + ks);
                #pragma unroll
                for (int i = 0; i < 8; ++i) {
                    float4 a4 = ar[i];
                    int kk = ks + i * 4;
                    xt[kk + 0][r] = a4.x; xt[kk + 1][r] = a4.y;
                    xt[kk + 2][r] = a4.z; xt[kk + 3][r] = a4.w;
                }
            } else {
                #pragma unroll
                for (int i = 0; i < 8; ++i) {
                    int kk = ks + i * 4;
                    xt[kk + 0][r] = 0.f; xt[kk + 1][r] = 0.f;
                    xt[kk + 2][r] = 0.f; xt[kk + 3][r] = 0.f;
                }
            }
        }
        __syncthreads();
        #pragma unroll 4
        for (int k = 0; k < 64; ++k) {
            float4 x0 = *reinterpret_cast<const float4*>(&xt[k][tn]);
            float4 x1 = *reinterpret_cast<const float4*>(&xt[k][tn + 4]);
            float4 w0 = *reinterpret_cast<const float4*>(&wt[k][to]);
            float4 w1 = *reinterpret_cast<const float4*>(&wt[k][to + 4]);
            float xv[8] = {x0.x, x0.y, x0.z, x0.w, x1.x, x1.y, x1.z, x1.w};
            float wv[8] = {w0.x, w0.y, w0.z, w0.w, w1.x, w1.y, w1.z, w1.w};
            #pragma unroll
            for (int i = 0; i < 8; ++i)
                #pragma unroll
                for (int j = 0; j < 8; ++j)
                    acc[i][j] = fmaf(xv[i], wv[j], acc[i][j]);
        }
        __syncthreads();
    }

    float bv[8];
    #pragma unroll
    for (int j = 0; j < 8; ++j) bv[j] = bias[to + j];
    #pragma unroll
    for (int i = 0; i < 8; ++i) {
        int n = row0 + tn + i;
        if (n >= n_nodes) break;
        float4 o0, o1;
        o0.x = fmaxf(acc[i][0] + bv[0], 0.f);
        o0.y = fmaxf(acc[i][1] + bv[1], 0.f);
        o0.z = fmaxf(acc[i][2] + bv[2], 0.f);
        o0.w = fmaxf(acc[i][3] + bv[3], 0.f);
        o1.x = fmaxf(acc[i][4] + bv[4], 0.f);
        o1.y = fmaxf(acc[i][5] + bv[5], 0.f);
        o1.z = fmaxf(acc[i][6] + bv[6], 0.f);
        o1.w = fmaxf(acc[i][7] + bv[7], 0.f);
        float* op = out + (size_t)n * FEAT + to;
        *reinterpret_cast<float4*>(op) = o0;
        *reinterpret_cast<float4*>(op + 4) = o1;
    }
}

extern "C" void kernel_launch(void* const* d_in, const int* in_sizes, int n_in,
                              void* d_out, int out_size, void* d_ws, size_t ws_size,
                              hipStream_t stream)
{
    const float* x     = (const float*)d_in[0];
    const int*   ei    = (const int*)d_in[1];
    const int*   batch = (const int*)d_in[2];
    const float* W1[3] = {(const float*)d_in[4], (const float*)d_in[8],  (const float*)d_in[12]};
    const float* b1[3] = {(const float*)d_in[5], (const float*)d_in[9],  (const float*)d_in[13]};
    const float* W2[3] = {(const float*)d_in[6], (const float*)d_in[10], (const float*)d_in[14]};
    const float* b2[3] = {(const float*)d_in[7], (const float*)d_in[11], (const float*)d_in[15]};

    const size_t nf = (size_t)NN * FEAT;
    float* outp = (float*)d_out;
    const int gemm_grid = (NN + 255) / 256;          // 391 (v3: 256 rows/block)
    const int M = NB * NCHUNK;                       // 78400
    const int scanM_blocks = (M + 1023) / 1024;      // 77
    const int WN = FEAT * FEAT;                      // 16384

    const size_t need_full = 3 * nf * 4 + (size_t)(NN + 1 + NE) * 4 + (size_t)12 * WN * 2;

    if (ws_size >= need_full) {
        short* xeffH = (short*)d_ws;           // nf shorts
        short* xeffL = xeffH + nf;             // nf shorts
        short* h1H   = xeffL + nf;             // nf shorts
        short* h1L   = h1H + nf;               // nf shorts
        float* bufC  = (float*)(h1L + nf);     // nf floats
        int* off     = (int*)(bufC + nf);      // NN+1
        int* csr     = off + (NN + 1);         // NE
        short* wbase = (short*)(csr + NE);     // 12 * WN shorts
        short* wf[6];                          // per weight: [2][16384] frag-major
        for (int i = 0; i < 6; ++i) wf[i] = wbase + (size_t)i * 2 * WN;
        // build transients aliased into plane space (planes written only after build)
        int* cnt_T  = (int*)xeffH;             // M
        int* offs_T = cnt_T + M;               // M
        int* bsum   = offs_T + M;              // 77
        int2* ebuf  = (int2*)h1H;              // NE pairs (12.8 MB)

        const float* Ws[6] = {W1[0], W2[0], W1[1], W2[1], W1[2], W2[2]};
        for (int i = 0; i < 6; ++i)
            wsplit_frag_kernel<<<WN / 256, 256, 0, stream>>>(Ws[i], wf[i]);

        p1a_count<<<NCHUNK, 256, 0, stream>>>(ei, cnt_T);
        scan1_kernel<<<scanM_blocks, 1024, 0, stream>>>(cnt_T, offs_T, bsum, M);
        scan2_kernel<<<1, 128, 0, stream>>>(bsum, scanM_blocks);
        scan3g_kernel<<<scanM_blocks, 1024, 0, stream>>>(offs_T, bsum, M);
        p1b_scatter<<<NCHUNK, 256, 0, stream>>>(ei, offs_T, ebuf);
        p2_csr<<<NB, 512, 0, stream>>>(ebuf, offs_T, off, csr);

        const float* h = x;
        for (int l = 0; l < 3; ++l) {
            aggregate_split_kernel<<<(NN + 3) / 4, 256, 0, stream>>>(h, off, csr, xeffH, xeffL, NN);
            gemm_mfma3_kernel<<<gemm_grid, 512, 0, stream>>>(xeffH, xeffL, wf[2 * l],
                                                             b1[l], nullptr, h1H, h1L, NN);
            gemm_mfma3_kernel<<<gemm_grid, 512, 0, stream>>>(h1H, h1L, wf[2 * l + 1],
                                                             b2[l], bufC, nullptr, nullptr, NN);
            pool_kernel<<<NGRAPH, 512, 0, stream>>>(bufC, batch, outp, NN, l);
            h = bufC;
        }
    } else if (ws_size >= 3 * nf * 4) {
        float* bufA = (float*)d_ws;
        float* bufB = bufA + nf;
        float* bufC = bufB + nf;
        const int gg = (NN + 127) / 128;
        const float* h = x;
        for (int l = 0; l < 3; ++l) {
            hipMemsetAsync(bufA, 0, nf * 4, stream);
            scatter_kernel<<<(NE + 3) / 4, 256, 0, stream>>>(h, ei, bufA, NE);
            combine_kernel<<<(int)((nf / 4 + 255) / 256), 256, 0, stream>>>(h, bufA, nf / 4);
            gemm_relu_kernel<<<gg, 256, 0, stream>>>(bufA, W1[l], b1[l], bufB, NN);
            gemm_relu_kernel<<<gg, 256, 0, stream>>>(bufB, W2[l], b2[l], bufC, NN);
            pool_kernel<<<NGRAPH, 512, 0, stream>>>(bufC, batch, outp, NN, l);
            h = bufC;
        }
    }
}

// Round 9
// 786.554 us; speedup vs baseline: 1.1766x; 1.0057x over previous
//
#include <hip/hip_runtime.h>

#define NN 100000
#define NE 1600000
#define FEAT 128
#define NGRAPH 128
#define BSHIFT 9
#define NB 196          // ceil(NN / 512)
#define NCHUNK 400
#define CHUNK 4000      // NE / NCHUNK exactly

typedef __attribute__((ext_vector_type(8))) short bf16x8;
typedef __attribute__((ext_vector_type(4))) float f32x4;

__device__ __forceinline__ unsigned short f2bf(float f) {
    unsigned u = __float_as_uint(f);
    return (unsigned short)((u + 0x7fffu + ((u >> 16) & 1u)) >> 16);  // RNE
}
__device__ __forceinline__ float bf2f(unsigned short h) {
    return __uint_as_float(((unsigned)h) << 16);
}

// ==================== W hi/lo split -> fragment-major layout ====================
__global__ __launch_bounds__(256)
void wsplit_frag_kernel(const float* __restrict__ W, short* __restrict__ Wf)
{
    int i = blockIdx.x * 256 + threadIdx.x;   // 16384 elements
    int o = i >> 7, k = i & 127;
    float f = W[i];
    unsigned short h = f2bf(f);
    short lo = (short)f2bf(f - bf2f(h));
    int ct = o >> 4, lr = o & 15, kc = k >> 5, q = (k >> 3) & 3, j = k & 7;
    int idx = (kc * 8 + ct) * 512 + ((q << 4) | lr) * 8 + j;
    Wf[idx] = (short)h;
    Wf[16384 + idx] = lo;
}

// ==================== radix-partition CSR build ====================
__global__ __launch_bounds__(256)
void p1a_count(const int* __restrict__ ei, int* __restrict__ cnt_T)
{
    __shared__ int hist[NB];
    const int b = blockIdx.x, tid = threadIdx.x;
    for (int i = tid; i < NB; i += 256) hist[i] = 0;
    __syncthreads();
    const int e0 = b * CHUNK;
    for (int e = e0 + tid; e < e0 + CHUNK; e += 256)
        atomicAdd(&hist[ei[NE + e] >> BSHIFT], 1);
    __syncthreads();
    for (int k = tid; k < NB; k += 256) cnt_T[k * NCHUNK + b] = hist[k];
}

__global__ __launch_bounds__(1024)
void scan1_kernel(const int* __restrict__ in, int* __restrict__ out,
                  int* __restrict__ bsum, int n)
{
    __shared__ int sh[1024];
    const int tid = threadIdx.x;
    const int gid = blockIdx.x * 1024 + tid;
    int v = (gid < n) ? in[gid] : 0;
    sh[tid] = v;
    __syncthreads();
    #pragma unroll
    for (int d = 1; d < 1024; d <<= 1) {
        int t = (tid >= d) ? sh[tid - d] : 0;
        __syncthreads();
        sh[tid] += t;
        __syncthreads();
    }
    if (gid < n) out[gid] = sh[tid] - v;
    if (tid == 1023) bsum[blockIdx.x] = sh[1023];
}

__global__ __launch_bounds__(128)
void scan2_kernel(int* __restrict__ bsum, int nb)
{
    __shared__ int sh[128];
    const int tid = threadIdx.x;
    int v = (tid < nb) ? bsum[tid] : 0;
    sh[tid] = v;
    __syncthreads();
    #pragma unroll
    for (int d = 1; d < 128; d <<= 1) {
        int t = (tid >= d) ? sh[tid - d] : 0;
        __syncthreads();
        sh[tid] += t;
        __syncthreads();
    }
    if (tid < nb) bsum[tid] = sh[tid] - v;
}

__global__ __launch_bounds__(1024)
void scan3g_kernel(int* __restrict__ arr, const int* __restrict__ bsum, int n)
{
    const int gid = blockIdx.x * 1024 + threadIdx.x;
    if (gid < n) arr[gid] += bsum[blockIdx.x];
}

__global__ __launch_bounds__(256)
void p1b_scatter(const int* __restrict__ ei, const int* __restrict__ offs_T,
                 int2* __restrict__ ebuf)
{
    __shared__ int cur[NB];
    const int b = blockIdx.x, tid = threadIdx.x;
    for (int i = tid; i < NB; i += 256) cur[i] = offs_T[i * NCHUNK + b];
    __syncthreads();
    const int e0 = b * CHUNK;
    for (int e = e0 + tid; e < e0 + CHUNK; e += 256) {
        int s = ei[e], d = ei[NE + e];
        int pos = atomicAdd(&cur[d >> BSHIFT], 1);
        ebuf[pos] = make_int2(s, d);
    }
}

__global__ __launch_bounds__(512)
void p2_csr(const int2* __restrict__ ebuf, const int* __restrict__ offs_T,
            int* __restrict__ off, int* __restrict__ csr)
{
    __shared__ int degc[512];
    __shared__ int sh[512];
    const int k = blockIdx.x, tid = threadIdx.x;
    const int base = k << BSHIFT;
    const int bs = offs_T[k * NCHUNK];
    const int be = (k == NB - 1) ? NE : offs_T[(k + 1) * NCHUNK];
    degc[tid] = 0;
    __syncthreads();
    for (int e = bs + tid; e < be; e += 512)
        atomicAdd(&degc[ebuf[e].y - base], 1);
    __syncthreads();
    int v = degc[tid];
    sh[tid] = v;
    __syncthreads();
    #pragma unroll
    for (int d = 1; d < 512; d <<= 1) {
        int t = (tid >= d) ? sh[tid - d] : 0;
        __syncthreads();
        sh[tid] += t;
        __syncthreads();
    }
    const int excl = bs + sh[tid] - v;
    const int n = base + tid;
    if (n <= NN) off[n] = excl;
    degc[tid] = excl;
    __syncthreads();
    for (int e = bs + tid; e < be; e += 512) {
        int2 p = ebuf[e];
        int slot = atomicAdd(&degc[p.y - base], 1);
        csr[slot] = p.x;
    }
}

// ==================== aggregation: xeff = (h + sum_in h[src]) * 0.5 + h, split hi/lo ====================
// MLP-deep version: 16 gathers in flight per wave before any consume; guarded adds for tails.
__global__ __launch_bounds__(256)
void aggregate_split_kernel(const float* __restrict__ h, const int* __restrict__ off,
                            const int* __restrict__ csr, short* __restrict__ xH,
                            short* __restrict__ xL, int nn)
{
    const int node = blockIdx.x * 4 + (threadIdx.x >> 6);
    if (node >= nn) return;
    const int lane = threadIdx.x & 63;
    const int s = off[node], e = off[node + 1];
    float2 acc = make_float2(0.f, 0.f);
    for (int base = s; base < e; base += 64) {
        const int cnt = min(64, e - base);
        // guarded lane load: lanes beyond cnt hold src 0 (valid row, masked out of the sum)
        int src_l = (base + lane < e) ? csr[base + lane] : 0;
        for (int jb = 0; jb < cnt; jb += 16) {
            float2 v[16];
            #pragma unroll
            for (int q = 0; q < 16; ++q) {
                int sq = __shfl(src_l, (jb + q) & 63);
                v[q] = reinterpret_cast<const float2*>(h + (size_t)sq * FEAT)[lane];
            }
            #pragma unroll
            for (int q = 0; q < 16; ++q) {
                if (jb + q < cnt) { acc.x += v[q].x; acc.y += v[q].y; }
            }
        }
    }
    float2 hv = reinterpret_cast<const float2*>(h + (size_t)node * FEAT)[lane];
    float ox = (hv.x + acc.x) * 0.5f + hv.x;
    float oy = (hv.y + acc.y) * 0.5f + hv.y;
    unsigned short hx = f2bf(ox), hy = f2bf(oy);
    short2 hi2 = make_short2((short)hx, (short)hy);
    short2 lo2 = make_short2((short)f2bf(ox - bf2f(hx)), (short)f2bf(oy - bf2f(hy)));
    reinterpret_cast<short2*>(xH + (size_t)node * FEAT)[lane] = hi2;
    reinterpret_cast<short2*>(xL + (size_t)node * FEAT)[lane] = lo2;
}

// ==================== MFMA split-bf16 GEMM v3: W in LDS (frag-major), A in regs ====================
__global__ __launch_bounds__(512)
void gemm_mfma3_kernel(const short* __restrict__ aH, const short* __restrict__ aL,
                       const short* __restrict__ Wf, const float* __restrict__ bias,
                       float* __restrict__ outF, short* __restrict__ outH,
                       short* __restrict__ outL, int n_nodes)
{
    __shared__ short wlds[32768];   // 64 KB: [hi|lo] frag-major
    const int tid = threadIdx.x;
    const int lane = tid & 63;
    const int w = tid >> 6;
    const int lr = lane & 15;
    const int lk = (lane >> 4) << 3;
    const int row0 = blockIdx.x * 256 + w * 32;

    // stage W: straight 64KB copy, lane-consecutive 16B chunks
    {
        const bf16x8* src = reinterpret_cast<const bf16x8*>(Wf);
        bf16x8* dst = reinterpret_cast<bf16x8*>(wlds);
        #pragma unroll
        for (int it = 0; it < 8; ++it)
            dst[it * 512 + tid] = src[it * 512 + tid];
    }

    // preload A fragments to registers
    const int r0 = row0 + lr;
    const int r1 = row0 + 16 + lr;
    const size_t rb0 = (size_t)r0 * FEAT + lk;
    const size_t rb1 = (size_t)r1 * FEAT + lk;
    const bool v0 = (r0 < n_nodes), v1 = (r1 < n_nodes);
    bf16x8 z = {};
    bf16x8 ah[4][2], al[4][2];
    #pragma unroll
    for (int kc = 0; kc < 4; ++kc) {
        ah[kc][0] = v0 ? *reinterpret_cast<const bf16x8*>(&aH[rb0 + kc * 32]) : z;
        al[kc][0] = v0 ? *reinterpret_cast<const bf16x8*>(&aL[rb0 + kc * 32]) : z;
        ah[kc][1] = v1 ? *reinterpret_cast<const bf16x8*>(&aH[rb1 + kc * 32]) : z;
        al[kc][1] = v1 ? *reinterpret_cast<const bf16x8*>(&aL[rb1 + kc * 32]) : z;
    }
    __syncthreads();

    f32x4 acc[2][8] = {};
    #pragma unroll
    for (int kc = 0; kc < 4; ++kc) {
        #pragma unroll
        for (int ct = 0; ct < 8; ++ct) {
            const int ra = (kc * 8 + ct) * 512 + lane * 8;
            bf16x8 bh = *reinterpret_cast<const bf16x8*>(&wlds[ra]);
            bf16x8 bl = *reinterpret_cast<const bf16x8*>(&wlds[16384 + ra]);
            #pragma unroll
            for (int rt = 0; rt < 2; ++rt) {
                acc[rt][ct] = __builtin_amdgcn_mfma_f32_16x16x32_bf16(ah[kc][rt], bh, acc[rt][ct], 0, 0, 0);
                acc[rt][ct] = __builtin_amdgcn_mfma_f32_16x16x32_bf16(al[kc][rt], bh, acc[rt][ct], 0, 0, 0);
                acc[rt][ct] = __builtin_amdgcn_mfma_f32_16x16x32_bf16(ah[kc][rt], bl, acc[rt][ct], 0, 0, 0);
            }
        }
    }

    // epilogue: C col = lane&15, row = (lane>>4)*4 + j
    #pragma unroll
    for (int rt = 0; rt < 2; ++rt) {
        const int rbase = row0 + rt * 16 + ((lane >> 4) << 2);
        #pragma unroll
        for (int ct = 0; ct < 8; ++ct) {
            const int col = ct * 16 + lr;
            const float b = bias[col];
            #pragma unroll
            for (int j = 0; j < 4; ++j) {
                const int n = rbase + j;
                if (n < n_nodes) {
                    float v = fmaxf(acc[rt][ct][j] + b, 0.f);
                    if (outF) {
                        outF[(size_t)n * FEAT + col] = v;
                    } else {
                        unsigned short hh = f2bf(v);
                        outH[(size_t)n * FEAT + col] = (short)hh;
                        outL[(size_t)n * FEAT + col] = (short)f2bf(v - bf2f(hh));
                    }
                }
            }
        }
    }
}

// ==================== pooling ====================
__global__ __launch_bounds__(512)
void pool_kernel(const float* __restrict__ y, const int* __restrict__ batch,
                 float* __restrict__ out, int n_nodes, int layer)
{
    const int g = blockIdx.x;
    int lo = 0, hi = n_nodes;
    while (lo < hi) { int mid = (lo + hi) >> 1; if (batch[mid] < g) lo = mid + 1; else hi = mid; }
    const int start = lo;
    hi = n_nodes;
    while (lo < hi) { int mid = (lo + hi) >> 1; if (batch[mid] < g + 1) lo = mid + 1; else hi = mid; }
    const int end = lo;

    const int tid = threadIdx.x;
    const int f = tid & 127;
    const int q = tid >> 7;
    float sum = 0.f;
    for (int n = start + q; n < end; n += 4)
        sum += y[(size_t)n * FEAT + f];

    __shared__ float red[512];
    red[tid] = sum;
    __syncthreads();
    if (tid < 128)
        out[g * (3 * FEAT) + layer * FEAT + tid]
            = red[tid] + red[tid + 128] + red[tid + 256] + red[tid + 384];
}

// ==================== fallback path kernels (ws too small) ====================
__global__ __launch_bounds__(256)
void scatter_kernel(const float* __restrict__ h, const int* __restrict__ ei,
                    float* __restrict__ agg, int n_edges)
{
    int e = blockIdx.x * 4 + (threadIdx.x >> 6);
    if (e >= n_edges) return;
    int lane = threadIdx.x & 63;
    int s = ei[e];
    int d = ei[n_edges + e];
    float2 v = reinterpret_cast<const float2*>(h + (size_t)s * FEAT)[lane];
    float* ap = agg + (size_t)d * FEAT + lane * 2;
    atomicAdd(ap, v.x);
    atomicAdd(ap + 1, v.y);
}

__global__ __launch_bounds__(256)
void combine_kernel(const float* __restrict__ h, float* __restrict__ agg_xeff, size_t n4)
{
    size_t i = (size_t)blockIdx.x * 256 + threadIdx.x;
    if (i >= n4) return;
    float4 a = reinterpret_cast<const float4*>(h)[i];
    float4 g = reinterpret_cast<float4*>(agg_xeff)[i];
    float4 o;
    o.x = (a.x + g.x) * 0.5f + a.x;
    o.y = (a.y + g.y) * 0.5f + a.y;
    o.z = (a.z + g.z) * 0.5f + a.z;
    o.w = (a.w + g.w) * 0.5f + a.w;
    reinterpret_cast<float4*>(agg_xeff)[i] = o;
}

__global__ __launch_bounds__(256, 2)
void gemm_relu_kernel(const float* __restrict__ A, const float* __restrict__ W,
                      const float* __restrict__ bias, float* __restrict__ out, int n_nodes)
{
    __shared__ float xt[64][128];
    __shared__ float wt[64][128];
    const int tid = threadIdx.x;
    const int row0 = blockIdx.x * 128;
    const int r  = tid >> 1;
    const int ks = (tid & 1) << 5;
    const int tn = (tid >> 4) << 3;
    const int to = (tid & 15) << 3;
    float acc[8][8] = {};

    for (int c = 0; c < 2; ++c) {
        const int k0 = c * 64;
        {
            const float4* wrow = reinterpret_cast<const float4*>(W + r * FEAT + k0 + ks);
            #pragma unroll
            for (int i = 0; i < 8; ++i) {
                float4 w4 = wrow[i];
                int kk = ks + i * 4;
                wt[kk + 0][r] = w4.x; wt[kk + 1][r] = w4.y;
                wt[kk + 2][r] = w4.z; wt[kk + 3][r] = w4.w;
            }
        }
        {
            const int n = row0 + r;
            if (n < n_nodes) {
                const float4* ar = reinterpret_cast<const float4*>(A + (size_t)n * FEAT + k0 + ks);
                #pragma unroll
                for (int i = 0; i < 8; ++i) {
                    float4 a4 = ar[i];
                    int kk = ks + i * 4;
                    xt[kk + 0][r] = a4.x; xt[kk + 1][r] = a4.y;
                    xt[kk + 2][r] = a4.z; xt[kk + 3][r] = a4.w;
                }
            } else {
                #pragma unroll
                for (int i = 0; i < 8; ++i) {
                    int kk = ks + i * 4;
                    xt[kk + 0][r] = 0.f; xt[kk + 1][r] = 0.f;
                    xt[kk + 2][r] = 0.f; xt[kk + 3][r] = 0.f;
                }
            }
        }
        __syncthreads();
        #pragma unroll 4
        for (int k = 0; k < 64; ++k) {
            float4 x0 = *reinterpret_cast<const float4*>(&xt[k][tn]);
            float4 x1 = *reinterpret_cast<const float4*>(&xt[k][tn + 4]);
            float4 w0 = *reinterpret_cast<const float4*>(&wt[k][to]);
            float4 w1 = *reinterpret_cast<const float4*>(&wt[k][to + 4]);
            float xv[8] = {x0.x, x0.y, x0.z, x0.w, x1.x, x1.y, x1.z, x1.w};
            float wv[8] = {w0.x, w0.y, w0.z, w0.w, w1.x, w1.y, w1.z, w1.w};
            #pragma unroll
            for (int i = 0; i < 8; ++i)
                #pragma unroll
                for (int j = 0; j < 8; ++j)
                    acc[i][j] = fmaf(xv[i], wv[j], acc[i][j]);
        }
        __syncthreads();
    }

    float bv[8];
    #pragma unroll
    for (int j = 0; j < 8; ++j) bv[j] = bias[to + j];
    #pragma unroll
    for (int i = 0; i < 8; ++i) {
        int n = row0 + tn + i;
        if (n >= n_nodes) break;
        float4 o0, o1;
        o0.x = fmaxf(acc[i][0] + bv[0], 0.f);
        o0.y = fmaxf(acc[i][1] + bv[1], 0.f);
        o0.z = fmaxf(acc[i][2] + bv[2], 0.f);
        o0.w = fmaxf(acc[i][3] + bv[3], 0.f);
        o1.x = fmaxf(acc[i][4] + bv[4], 0.f);
        o1.y = fmaxf(acc[i][5] + bv[5], 0.f);
        o1.z = fmaxf(acc[i][6] + bv[6], 0.f);
        o1.w = fmaxf(acc[i][7] + bv[7], 0.f);
        float* op = out + (size_t)n * FEAT + to;
        *reinterpret_cast<float4*>(op) = o0;
        *reinterpret_cast<float4*>(op + 4) = o1;
    }
}

extern "C" void kernel_launch(void* const* d_in, const int* in_sizes, int n_in,
                              void* d_out, int out_size, void* d_ws, size_t ws_size,
                              hipStream_t stream)
{
    const float* x     = (const float*)d_in[0];
    const int*   ei    = (const int*)d_in[1];
    const int*   batch = (const int*)d_in[2];
    const float* W1[3] = {(const float*)d_in[4], (const float*)d_in[8],  (const float*)d_in[12]};
    const float* b1[3] = {(const float*)d_in[5], (const float*)d_in[9],  (const float*)d_in[13]};
    const float* W2[3] = {(const float*)d_in[6], (const float*)d_in[10], (const float*)d_in[14]};
    const float* b2[3] = {(const float*)d_in[7], (const float*)d_in[11], (const float*)d_in[15]};

    const size_t nf = (size_t)NN * FEAT;
    float* outp = (float*)d_out;
    const int gemm_grid = (NN + 255) / 256;          // 391 (v3: 256 rows/block)
    const int M = NB * NCHUNK;                       // 78400
    const int scanM_blocks = (M + 1023) / 1024;      // 77
    const int WN = FEAT * FEAT;                      // 16384

    const size_t need_full = 3 * nf * 4 + (size_t)(NN + 1 + NE) * 4 + (size_t)12 * WN * 2;

    if (ws_size >= need_full) {
        short* xeffH = (short*)d_ws;           // nf shorts
        short* xeffL = xeffH + nf;             // nf shorts
        short* h1H   = xeffL + nf;             // nf shorts
        short* h1L   = h1H + nf;               // nf shorts
        float* bufC  = (float*)(h1L + nf);     // nf floats
        int* off     = (int*)(bufC + nf);      // NN+1
        int* csr     = off + (NN + 1);         // NE
        short* wbase = (short*)(csr + NE);     // 12 * WN shorts
        short* wf[6];                          // per weight: [2][16384] frag-major
        for (int i = 0; i < 6; ++i) wf[i] = wbase + (size_t)i * 2 * WN;
        // build transients aliased into plane space (planes written only after build)
        int* cnt_T  = (int*)xeffH;             // M
        int* offs_T = cnt_T + M;               // M
        int* bsum   = offs_T + M;              // 77
        int2* ebuf  = (int2*)h1H;              // NE pairs (12.8 MB)

        const float* Ws[6] = {W1[0], W2[0], W1[1], W2[1], W1[2], W2[2]};
        for (int i = 0; i < 6; ++i)
            wsplit_frag_kernel<<<WN / 256, 256, 0, stream>>>(Ws[i], wf[i]);

        p1a_count<<<NCHUNK, 256, 0, stream>>>(ei, cnt_T);
        scan1_kernel<<<scanM_blocks, 1024, 0, stream>>>(cnt_T, offs_T, bsum, M);
        scan2_kernel<<<1, 128, 0, stream>>>(bsum, scanM_blocks);
        scan3g_kernel<<<scanM_blocks, 1024, 0, stream>>>(offs_T, bsum, M);
        p1b_scatter<<<NCHUNK, 256, 0, stream>>>(ei, offs_T, ebuf);
        p2_csr<<<NB, 512, 0, stream>>>(ebuf, offs_T, off, csr);

        const float* h = x;
        for (int l = 0; l < 3; ++l) {
            aggregate_split_kernel<<<(NN + 3) / 4, 256, 0, stream>>>(h, off, csr, xeffH, xeffL, NN);
            gemm_mfma3_kernel<<<gemm_grid, 512, 0, stream>>>(xeffH, xeffL, wf[2 * l],
                                                             b1[l], nullptr, h1H, h1L, NN);
            gemm_mfma3_kernel<<<gemm_grid, 512, 0, stream>>>(h1H, h1L, wf[2 * l + 1],
                                                             b2[l], bufC, nullptr, nullptr, NN);
            pool_kernel<<<NGRAPH, 512, 0, stream>>>(bufC, batch, outp, NN, l);
            h = bufC;
        }
    } else if (ws_size >= 3 * nf * 4) {
        float* bufA = (float*)d_ws;
        float* bufB = bufA + nf;
        float* bufC = bufB + nf;
        const int gg = (NN + 127) / 128;
        const float* h = x;
        for (int l = 0; l < 3; ++l) {
            hipMemsetAsync(bufA, 0, nf * 4, stream);
            scatter_kernel<<<(NE + 3) / 4, 256, 0, stream>>>(h, ei, bufA, NE);
            combine_kernel<<<(int)((nf / 4 + 255) / 256), 256, 0, stream>>>(h, bufA, nf / 4);
            gemm_relu_kernel<<<gg, 256, 0, stream>>>(bufA, W1[l], b1[l], bufB, NN);
            gemm_relu_kernel<<<gg, 256, 0, stream>>>(bufB, W2[l], b2[l], bufC, NN);
            pool_kernel<<<NGRAPH, 512, 0, stream>>>(bufC, batch, outp, NN, l);
            h = bufC;
        }
    }
}

// Round 10
// 729.992 us; speedup vs baseline: 1.2678x; 1.0775x over previous
//
#include <hip/hip_runtime.h>

#define NN 100000
#define NE 1600000
#define FEAT 128
#define NGRAPH 128
#define BSHIFT 9
#define NB 196          // ceil(NN / 512)
#define NCHUNK 400
#define CHUNK 4000      // NE / NCHUNK exactly

typedef __attribute__((ext_vector_type(8))) short bf16x8;
typedef __attribute__((ext_vector_type(4))) float f32x4;

__device__ __forceinline__ unsigned short f2bf(float f) {
    unsigned u = __float_as_uint(f);
    return (unsigned short)((u + 0x7fffu + ((u >> 16) & 1u)) >> 16);  // RNE
}
__device__ __forceinline__ float bf2f(unsigned short h) {
    return __uint_as_float(((unsigned)h) << 16);
}

// ==================== W hi/lo split -> fragment-major layout ====================
__global__ __launch_bounds__(256)
void wsplit_frag_kernel(const float* __restrict__ W, short* __restrict__ Wf)
{
    int i = blockIdx.x * 256 + threadIdx.x;   // 16384 elements
    int o = i >> 7, k = i & 127;
    float f = W[i];
    unsigned short h = f2bf(f);
    short lo = (short)f2bf(f - bf2f(h));
    int ct = o >> 4, lr = o & 15, kc = k >> 5, q = (k >> 3) & 3, j = k & 7;
    int idx = (kc * 8 + ct) * 512 + ((q << 4) | lr) * 8 + j;
    Wf[idx] = (short)h;
    Wf[16384 + idx] = lo;
}

// ==================== radix-partition CSR build ====================
__global__ __launch_bounds__(256)
void p1a_count(const int* __restrict__ ei, int* __restrict__ cnt_T)
{
    __shared__ int hist[NB];
    const int b = blockIdx.x, tid = threadIdx.x;
    for (int i = tid; i < NB; i += 256) hist[i] = 0;
    __syncthreads();
    const int e0 = b * CHUNK;
    for (int e = e0 + tid; e < e0 + CHUNK; e += 256)
        atomicAdd(&hist[ei[NE + e] >> BSHIFT], 1);
    __syncthreads();
    for (int k = tid; k < NB; k += 256) cnt_T[k * NCHUNK + b] = hist[k];
}

__global__ __launch_bounds__(1024)
void scan1_kernel(const int* __restrict__ in, int* __restrict__ out,
                  int* __restrict__ bsum, int n)
{
    __shared__ int sh[1024];
    const int tid = threadIdx.x;
    const int gid = blockIdx.x * 1024 + tid;
    int v = (gid < n) ? in[gid] : 0;
    sh[tid] = v;
    __syncthreads();
    #pragma unroll
    for (int d = 1; d < 1024; d <<= 1) {
        int t = (tid >= d) ? sh[tid - d] : 0;
        __syncthreads();
        sh[tid] += t;
        __syncthreads();
    }
    if (gid < n) out[gid] = sh[tid] - v;
    if (tid == 1023) bsum[blockIdx.x] = sh[1023];
}

__global__ __launch_bounds__(128)
void scan2_kernel(int* __restrict__ bsum, int nb)
{
    __shared__ int sh[128];
    const int tid = threadIdx.x;
    int v = (tid < nb) ? bsum[tid] : 0;
    sh[tid] = v;
    __syncthreads();
    #pragma unroll
    for (int d = 1; d < 128; d <<= 1) {
        int t = (tid >= d) ? sh[tid - d] : 0;
        __syncthreads();
        sh[tid] += t;
        __syncthreads();
    }
    if (tid < nb) bsum[tid] = sh[tid] - v;
}

__global__ __launch_bounds__(1024)
void scan3g_kernel(int* __restrict__ arr, const int* __restrict__ bsum, int n)
{
    const int gid = blockIdx.x * 1024 + threadIdx.x;
    if (gid < n) arr[gid] += bsum[blockIdx.x];
}

__global__ __launch_bounds__(256)
void p1b_scatter(const int* __restrict__ ei, const int* __restrict__ offs_T,
                 int2* __restrict__ ebuf)
{
    __shared__ int cur[NB];
    const int b = blockIdx.x, tid = threadIdx.x;
    for (int i = tid; i < NB; i += 256) cur[i] = offs_T[i * NCHUNK + b];
    __syncthreads();
    const int e0 = b * CHUNK;
    for (int e = e0 + tid; e < e0 + CHUNK; e += 256) {
        int s = ei[e], d = ei[NE + e];
        int pos = atomicAdd(&cur[d >> BSHIFT], 1);
        ebuf[pos] = make_int2(s, d);
    }
}

__global__ __launch_bounds__(512)
void p2_csr(const int2* __restrict__ ebuf, const int* __restrict__ offs_T,
            int* __restrict__ off, int* __restrict__ csr)
{
    __shared__ int degc[512];
    __shared__ int sh[512];
    const int k = blockIdx.x, tid = threadIdx.x;
    const int base = k << BSHIFT;
    const int bs = offs_T[k * NCHUNK];
    const int be = (k == NB - 1) ? NE : offs_T[(k + 1) * NCHUNK];
    degc[tid] = 0;
    __syncthreads();
    for (int e = bs + tid; e < be; e += 512)
        atomicAdd(&degc[ebuf[e].y - base], 1);
    __syncthreads();
    int v = degc[tid];
    sh[tid] = v;
    __syncthreads();
    #pragma unroll
    for (int d = 1; d < 512; d <<= 1) {
        int t = (tid >= d) ? sh[tid - d] : 0;
        __syncthreads();
        sh[tid] += t;
        __syncthreads();
    }
    const int excl = bs + sh[tid] - v;
    const int n = base + tid;
    if (n <= NN) off[n] = excl;
    degc[tid] = excl;
    __syncthreads();
    for (int e = bs + tid; e < be; e += 512) {
        int2 p = ebuf[e];
        int slot = atomicAdd(&degc[p.y - base], 1);
        csr[slot] = p.x;
    }
}

// ==================== aggregation: xeff = (h + sum_in h[src]) * 0.5 + h, split hi/lo ====================
__global__ __launch_bounds__(256)
void aggregate_split_kernel(const float* __restrict__ h, const int* __restrict__ off,
                            const int* __restrict__ csr, short* __restrict__ xH,
                            short* __restrict__ xL, int nn)
{
    const int node = blockIdx.x * 4 + (threadIdx.x >> 6);
    if (node >= nn) return;
    const int lane = threadIdx.x & 63;
    const int s = off[node], e = off[node + 1];
    float2 acc = make_float2(0.f, 0.f);
    for (int base = s; base < e; base += 64) {
        const int cnt = min(64, e - base);
        int src_l = (base + lane < e) ? csr[base + lane] : 0;
        for (int jb = 0; jb < cnt; jb += 16) {
            float2 v[16];
            #pragma unroll
            for (int q = 0; q < 16; ++q) {
                int sq = __shfl(src_l, (jb + q) & 63);
                v[q] = reinterpret_cast<const float2*>(h + (size_t)sq * FEAT)[lane];
            }
            #pragma unroll
            for (int q = 0; q < 16; ++q) {
                if (jb + q < cnt) { acc.x += v[q].x; acc.y += v[q].y; }
            }
        }
    }
    float2 hv = reinterpret_cast<const float2*>(h + (size_t)node * FEAT)[lane];
    float ox = (hv.x + acc.x) * 0.5f + hv.x;
    float oy = (hv.y + acc.y) * 0.5f + hv.y;
    unsigned short hx = f2bf(ox), hy = f2bf(oy);
    short2 hi2 = make_short2((short)hx, (short)hy);
    short2 lo2 = make_short2((short)f2bf(ox - bf2f(hx)), (short)f2bf(oy - bf2f(hy)));
    reinterpret_cast<short2*>(xH + (size_t)node * FEAT)[lane] = hi2;
    reinterpret_cast<short2*>(xL + (size_t)node * FEAT)[lane] = lo2;
}

// ==================== MFMA split-bf16 GEMM v4: W in LDS, per-kc A loads, 2 blocks/CU ====================
// C = Ah*Wh + Al*Wh + Ah*Wl. Block: 512 threads = 8 waves x 32 rows = 256 rows.
// __launch_bounds__(512,4): cap VGPR at 128 -> 2 blocks/CU (16 waves, LDS 2x64KB=128<=160KB).
__global__ __launch_bounds__(512, 4)
void gemm_mfma4_kernel(const short* __restrict__ aH, const short* __restrict__ aL,
                       const short* __restrict__ Wf, const float* __restrict__ bias,
                       float* __restrict__ outF, short* __restrict__ outH,
                       short* __restrict__ outL, int n_nodes)
{
    __shared__ short wlds[32768];   // 64 KB: [hi|lo] frag-major
    const int tid = threadIdx.x;
    const int lane = tid & 63;
    const int w = tid >> 6;
    const int lr = lane & 15;
    const int lk = (lane >> 4) << 3;
    const int row0 = blockIdx.x * 256 + w * 32;

    // stage W: straight 64KB copy, lane-consecutive 16B chunks
    {
        const bf16x8* src = reinterpret_cast<const bf16x8*>(Wf);
        bf16x8* dst = reinterpret_cast<bf16x8*>(wlds);
        #pragma unroll
        for (int it = 0; it < 8; ++it)
            dst[it * 512 + tid] = src[it * 512 + tid];
    }

    const int r0 = row0 + lr;
    const int r1 = row0 + 16 + lr;
    const size_t rb0 = (size_t)r0 * FEAT + lk;
    const size_t rb1 = (size_t)r1 * FEAT + lk;
    const bool v0 = (r0 < n_nodes), v1 = (r1 < n_nodes);
    bf16x8 z = {};

    // kc=0 A-frags issued before the barrier (latency hides under W-stage drain)
    bf16x8 c0h = v0 ? *reinterpret_cast<const bf16x8*>(&aH[rb0]) : z;
    bf16x8 c0l = v0 ? *reinterpret_cast<const bf16x8*>(&aL[rb0]) : z;
    bf16x8 c1h = v1 ? *reinterpret_cast<const bf16x8*>(&aH[rb1]) : z;
    bf16x8 c1l = v1 ? *reinterpret_cast<const bf16x8*>(&aL[rb1]) : z;
    __syncthreads();

    f32x4 acc[2][8] = {};
    #pragma unroll
    for (int kc = 0; kc < 4; ++kc) {
        bf16x8 n0h = z, n0l = z, n1h = z, n1l = z;
        if (kc < 3) {
            const int ko = (kc + 1) * 32;
            n0h = v0 ? *reinterpret_cast<const bf16x8*>(&aH[rb0 + ko]) : z;
            n0l = v0 ? *reinterpret_cast<const bf16x8*>(&aL[rb0 + ko]) : z;
            n1h = v1 ? *reinterpret_cast<const bf16x8*>(&aH[rb1 + ko]) : z;
            n1l = v1 ? *reinterpret_cast<const bf16x8*>(&aL[rb1 + ko]) : z;
        }
        #pragma unroll
        for (int ct = 0; ct < 8; ++ct) {
            const int ra = (kc * 8 + ct) * 512 + lane * 8;
            bf16x8 bh = *reinterpret_cast<const bf16x8*>(&wlds[ra]);
            bf16x8 bl = *reinterpret_cast<const bf16x8*>(&wlds[16384 + ra]);
            acc[0][ct] = __builtin_amdgcn_mfma_f32_16x16x32_bf16(c0h, bh, acc[0][ct], 0, 0, 0);
            acc[0][ct] = __builtin_amdgcn_mfma_f32_16x16x32_bf16(c0l, bh, acc[0][ct], 0, 0, 0);
            acc[0][ct] = __builtin_amdgcn_mfma_f32_16x16x32_bf16(c0h, bl, acc[0][ct], 0, 0, 0);
            acc[1][ct] = __builtin_amdgcn_mfma_f32_16x16x32_bf16(c1h, bh, acc[1][ct], 0, 0, 0);
            acc[1][ct] = __builtin_amdgcn_mfma_f32_16x16x32_bf16(c1l, bh, acc[1][ct], 0, 0, 0);
            acc[1][ct] = __builtin_amdgcn_mfma_f32_16x16x32_bf16(c1h, bl, acc[1][ct], 0, 0, 0);
        }
        c0h = n0h; c0l = n0l; c1h = n1h; c1l = n1l;
    }

    // epilogue: C col = lane&15, row = (lane>>4)*4 + j
    #pragma unroll
    for (int rt = 0; rt < 2; ++rt) {
        const int rbase = row0 + rt * 16 + ((lane >> 4) << 2);
        #pragma unroll
        for (int ct = 0; ct < 8; ++ct) {
            const int col = ct * 16 + lr;
            const float b = bias[col];
            #pragma unroll
            for (int j = 0; j < 4; ++j) {
                const int n = rbase + j;
                if (n < n_nodes) {
                    float v = fmaxf(acc[rt][ct][j] + b, 0.f);
                    if (outF) {
                        outF[(size_t)n * FEAT + col] = v;
                    } else {
                        unsigned short hh = f2bf(v);
                        outH[(size_t)n * FEAT + col] = (short)hh;
                        outL[(size_t)n * FEAT + col] = (short)f2bf(v - bf2f(hh));
                    }
                }
            }
        }
    }
}

// ==================== pooling ====================
__global__ __launch_bounds__(512)
void pool_kernel(const float* __restrict__ y, const int* __restrict__ batch,
                 float* __restrict__ out, int n_nodes, int layer)
{
    const int g = blockIdx.x;
    int lo = 0, hi = n_nodes;
    while (lo < hi) { int mid = (lo + hi) >> 1; if (batch[mid] < g) lo = mid + 1; else hi = mid; }
    const int start = lo;
    hi = n_nodes;
    while (lo < hi) { int mid = (lo + hi) >> 1; if (batch[mid] < g + 1) lo = mid + 1; else hi = mid; }
    const int end = lo;

    const int tid = threadIdx.x;
    const int f = tid & 127;
    const int q = tid >> 7;
    float sum = 0.f;
    for (int n = start + q; n < end; n += 4)
        sum += y[(size_t)n * FEAT + f];

    __shared__ float red[512];
    red[tid] = sum;
    __syncthreads();
    if (tid < 128)
        out[g * (3 * FEAT) + layer * FEAT + tid]
            = red[tid] + red[tid + 128] + red[tid + 256] + red[tid + 384];
}

// ==================== fallback path kernels (ws too small) ====================
__global__ __launch_bounds__(256)
void scatter_kernel(const float* __restrict__ h, const int* __restrict__ ei,
                    float* __restrict__ agg, int n_edges)
{
    int e = blockIdx.x * 4 + (threadIdx.x >> 6);
    if (e >= n_edges) return;
    int lane = threadIdx.x & 63;
    int s = ei[e];
    int d = ei[n_edges + e];
    float2 v = reinterpret_cast<const float2*>(h + (size_t)s * FEAT)[lane];
    float* ap = agg + (size_t)d * FEAT + lane * 2;
    atomicAdd(ap, v.x);
    atomicAdd(ap + 1, v.y);
}

__global__ __launch_bounds__(256)
void combine_kernel(const float* __restrict__ h, float* __restrict__ agg_xeff, size_t n4)
{
    size_t i = (size_t)blockIdx.x * 256 + threadIdx.x;
    if (i >= n4) return;
    float4 a = reinterpret_cast<const float4*>(h)[i];
    float4 g = reinterpret_cast<float4*>(agg_xeff)[i];
    float4 o;
    o.x = (a.x + g.x) * 0.5f + a.x;
    o.y = (a.y + g.y) * 0.5f + a.y;
    o.z = (a.z + g.z) * 0.5f + a.z;
    o.w = (a.w + g.w) * 0.5f + a.w;
    reinterpret_cast<float4*>(agg_xeff)[i] = o;
}

__global__ __launch_bounds__(256, 2)
void gemm_relu_kernel(const float* __restrict__ A, const float* __restrict__ W,
                      const float* __restrict__ bias, float* __restrict__ out, int n_nodes)
{
    __shared__ float xt[64][128];
    __shared__ float wt[64][128];
    const int tid = threadIdx.x;
    const int row0 = blockIdx.x * 128;
    const int r  = tid >> 1;
    const int ks = (tid & 1) << 5;
    const int tn = (tid >> 4) << 3;
    const int to = (tid & 15) << 3;
    float acc[8][8] = {};

    for (int c = 0; c < 2; ++c) {
        const int k0 = c * 64;
        {
            const float4* wrow = reinterpret_cast<const float4*>(W + r * FEAT + k0 + ks);
            #pragma unroll
            for (int i = 0; i < 8; ++i) {
                float4 w4 = wrow[i];
                int kk = ks + i * 4;
                wt[kk + 0][r] = w4.x; wt[kk + 1][r] = w4.y;
                wt[kk + 2][r] = w4.z; wt[kk + 3][r] = w4.w;
            }
        }
        {
            const int n = row0 + r;
            if (n < n_nodes) {
                const float4* ar = reinterpret_cast<const float4*>(A + (size_t)n * FEAT + k0 + ks);
                #pragma unroll
                for (int i = 0; i < 8; ++i) {
                    float4 a4 = ar[i];
                    int kk = ks + i * 4;
                    xt[kk + 0][r] = a4.x; xt[kk + 1][r] = a4.y;
                    xt[kk + 2][r] = a4.z; xt[kk + 3][r] = a4.w;
                }
            } else {
                #pragma unroll
                for (int i = 0; i < 8; ++i) {
                    int kk = ks + i * 4;
                    xt[kk + 0][r] = 0.f; xt[kk + 1][r] = 0.f;
                    xt[kk + 2][r] = 0.f; xt[kk + 3][r] = 0.f;
                }
            }
        }
        __syncthreads();
        #pragma unroll 4
        for (int k = 0; k < 64; ++k) {
            float4 x0 = *reinterpret_cast<const float4*>(&xt[k][tn]);
            float4 x1 = *reinterpret_cast<const float4*>(&xt[k][tn + 4]);
            float4 w0 = *reinterpret_cast<const float4*>(&wt[k][to]);
            float4 w1 = *reinterpret_cast<const float4*>(&wt[k][to + 4]);
            float xv[8] = {x0.x, x0.y, x0.z, x0.w, x1.x, x1.y, x1.z, x1.w};
            float wv[8] = {w0.x, w0.y, w0.z, w0.w, w1.x, w1.y, w1.z, w1.w};
            #pragma unroll
            for (int i = 0; i < 8; ++i)
                #pragma unroll
                for (int j = 0; j < 8; ++j)
                    acc[i][j] = fmaf(xv[i], wv[j], acc[i][j]);
        }
        __syncthreads();
    }

    float bv[8];
    #pragma unroll
    for (int j = 0; j < 8; ++j) bv[j] = bias[to + j];
    #pragma unroll
    for (int i = 0; i < 8; ++i) {
        int n = row0 + tn + i;
        if (n >= n_nodes) break;
        float4 o0, o1;
        o0.x = fmaxf(acc[i][0] + bv[0], 0.f);
        o0.y = fmaxf(acc[i][1] + bv[1], 0.f);
        o0.z = fmaxf(acc[i][2] + bv[2], 0.f);
        o0.w = fmaxf(acc[i][3] + bv[3], 0.f);
        o1.x = fmaxf(acc[i][4] + bv[4], 0.f);
        o1.y = fmaxf(acc[i][5] + bv[5], 0.f);
        o1.z = fmaxf(acc[i][6] + bv[6], 0.f);
        o1.w = fmaxf(acc[i][7] + bv[7], 0.f);
        float* op = out + (size_t)n * FEAT + to;
        *reinterpret_cast<float4*>(op) = o0;
        *reinterpret_cast<float4*>(op + 4) = o1;
    }
}

extern "C" void kernel_launch(void* const* d_in, const int* in_sizes, int n_in,
                              void* d_out, int out_size, void* d_ws, size_t ws_size,
                              hipStream_t stream)
{
    const float* x     = (const float*)d_in[0];
    const int*   ei    = (const int*)d_in[1];
    const int*   batch = (const int*)d_in[2];
    const float* W1[3] = {(const float*)d_in[4], (const float*)d_in[8],  (const float*)d_in[12]};
    const float* b1[3] = {(const float*)d_in[5], (const float*)d_in[9],  (const float*)d_in[13]};
    const float* W2[3] = {(const float*)d_in[6], (const float*)d_in[10], (const float*)d_in[14]};
    const float* b2[3] = {(const float*)d_in[7], (const float*)d_in[11], (const float*)d_in[15]};

    const size_t nf = (size_t)NN * FEAT;
    float* outp = (float*)d_out;
    const int gemm_grid = (NN + 255) / 256;          // 391
    const int M = NB * NCHUNK;                       // 78400
    const int scanM_blocks = (M + 1023) / 1024;      // 77
    const int WN = FEAT * FEAT;                      // 16384

    const size_t need_full = 3 * nf * 4 + (size_t)(NN + 1 + NE) * 4 + (size_t)12 * WN * 2;

    if (ws_size >= need_full) {
        short* xeffH = (short*)d_ws;           // nf shorts
        short* xeffL = xeffH + nf;             // nf shorts
        short* h1H   = xeffL + nf;             // nf shorts
        short* h1L   = h1H + nf;               // nf shorts
        float* bufC  = (float*)(h1L + nf);     // nf floats
        int* off     = (int*)(bufC + nf);      // NN+1
        int* csr     = off + (NN + 1);         // NE
        short* wbase = (short*)(csr + NE);     // 12 * WN shorts
        short* wf[6];                          // per weight: [2][16384] frag-major
        for (int i = 0; i < 6; ++i) wf[i] = wbase + (size_t)i * 2 * WN;
        // build transients aliased into plane space (planes written only after build)
        int* cnt_T  = (int*)xeffH;             // M
        int* offs_T = cnt_T + M;               // M
        int* bsum   = offs_T + M;              // 77
        int2* ebuf  = (int2*)h1H;              // NE pairs (12.8 MB)

        const float* Ws[6] = {W1[0], W2[0], W1[1], W2[1], W1[2], W2[2]};
        for (int i = 0; i < 6; ++i)
            wsplit_frag_kernel<<<WN / 256, 256, 0, stream>>>(Ws[i], wf[i]);

        p1a_count<<<NCHUNK, 256, 0, stream>>>(ei, cnt_T);
        scan1_kernel<<<scanM_blocks, 1024, 0, stream>>>(cnt_T, offs_T, bsum, M);
        scan2_kernel<<<1, 128, 0, stream>>>(bsum, scanM_blocks);
        scan3g_kernel<<<scanM_blocks, 1024, 0, stream>>>(offs_T, bsum, M);
        p1b_scatter<<<NCHUNK, 256, 0, stream>>>(ei, offs_T, ebuf);
        p2_csr<<<NB, 512, 0, stream>>>(ebuf, offs_T, off, csr);

        const float* h = x;
        for (int l = 0; l < 3; ++l) {
            aggregate_split_kernel<<<(NN + 3) / 4, 256, 0, stream>>>(h, off, csr, xeffH, xeffL, NN);
            gemm_mfma4_kernel<<<gemm_grid, 512, 0, stream>>>(xeffH, xeffL, wf[2 * l],
                                                             b1[l], nullptr, h1H, h1L, NN);
            gemm_mfma4_kernel<<<gemm_grid, 512, 0, stream>>>(h1H, h1L, wf[2 * l + 1],
                                                             b2[l], bufC, nullptr, nullptr, NN);
            pool_kernel<<<NGRAPH, 512, 0, stream>>>(bufC, batch, outp, NN, l);
            h = bufC;
        }
    } else if (ws_size >= 3 * nf * 4) {
        float* bufA = (float*)d_ws;
        float* bufB = bufA + nf;
        float* bufC = bufB + nf;
        const int gg = (NN + 127) / 128;
        const float* h = x;
        for (int l = 0; l < 3; ++l) {
            hipMemsetAsync(bufA, 0, nf * 4, stream);
            scatter_kernel<<<(NE + 3) / 4, 256, 0, stream>>>(h, ei, bufA, NE);
            combine_kernel<<<(int)((nf / 4 + 255) / 256), 256, 0, stream>>>(h, bufA, nf / 4);
            gemm_relu_kernel<<<gg, 256, 0, stream>>>(bufA, W1[l], b1[l], bufB, NN);
            gemm_relu_kernel<<<gg, 256, 0, stream>>>(bufB, W2[l], b2[l], bufC, NN);
            pool_kernel<<<NGRAPH, 512, 0, stream>>>(bufC, batch, outp, NN, l);
            h = bufC;
        }
    }
}

// Round 12
// 721.783 us; speedup vs baseline: 1.2822x; 1.0114x over previous
//
#include <hip/hip_runtime.h>

#define NN 100000
#define NE 1600000
#define FEAT 128
#define NGRAPH 128
#define BSHIFT 9
#define NB 196          // ceil(NN / 512)
#define NCHUNK 400
#define CHUNK 4000      // NE / NCHUNK exactly

typedef __attribute__((ext_vector_type(8))) short bf16x8;
typedef __attribute__((ext_vector_type(4))) float f32x4;
typedef __attribute__((ext_vector_type(4))) unsigned u32x4;

union U4 { u32x4 u; bf16x8 v; };

__device__ __forceinline__ unsigned short f2bf(float f) {
    unsigned u = __float_as_uint(f);
    return (unsigned short)((u + 0x7fffu + ((u >> 16) & 1u)) >> 16);  // RNE
}
__device__ __forceinline__ float bf2f(unsigned short h) {
    return __uint_as_float(((unsigned)h) << 16);
}
// two packed (hi|lo<<16) dwords -> {hi-pair dword, lo-pair dword} (by value: vector
// elements can't bind to non-const refs)
__device__ __forceinline__ uint2 unpack2(unsigned p0, unsigned p1) {
    return make_uint2((p0 & 0xffffu) | (p1 << 16), (p0 >> 16) | (p1 & 0xffff0000u));
}
// unpack a u32x4 pair (8 packed elems) into hi-plane / lo-plane bf16x8
__device__ __forceinline__ void unpack8(u32x4 a, u32x4 b, bf16x8& hv, bf16x8& lv) {
    uint2 r0 = unpack2(a.x, a.y), r1 = unpack2(a.z, a.w);
    uint2 r2 = unpack2(b.x, b.y), r3 = unpack2(b.z, b.w);
    U4 h, l;
    h.u = (u32x4){r0.x, r1.x, r2.x, r3.x};
    l.u = (u32x4){r0.y, r1.y, r2.y, r3.y};
    hv = h.v; lv = l.v;
}

// ==================== W hi/lo split -> fragment-major layout ====================
__global__ __launch_bounds__(256)
void wsplit_frag_kernel(const float* __restrict__ W, short* __restrict__ Wf)
{
    int i = blockIdx.x * 256 + threadIdx.x;   // 16384 elements
    int o = i >> 7, k = i & 127;
    float f = W[i];
    unsigned short h = f2bf(f);
    short lo = (short)f2bf(f - bf2f(h));
    int ct = o >> 4, lr = o & 15, kc = k >> 5, q = (k >> 3) & 3, j = k & 7;
    int idx = (kc * 8 + ct) * 512 + ((q << 4) | lr) * 8 + j;
    Wf[idx] = (short)h;
    Wf[16384 + idx] = lo;
}

// ==================== radix-partition CSR build ====================
__global__ __launch_bounds__(256)
void p1a_count(const int* __restrict__ ei, int* __restrict__ cnt_T)
{
    __shared__ int hist[NB];
    const int b = blockIdx.x, tid = threadIdx.x;
    for (int i = tid; i < NB; i += 256) hist[i] = 0;
    __syncthreads();
    const int e0 = b * CHUNK;
    for (int e = e0 + tid; e < e0 + CHUNK; e += 256)
        atomicAdd(&hist[ei[NE + e] >> BSHIFT], 1);
    __syncthreads();
    for (int k = tid; k < NB; k += 256) cnt_T[k * NCHUNK + b] = hist[k];
}

__global__ __launch_bounds__(1024)
void scan1_kernel(const int* __restrict__ in, int* __restrict__ out,
                  int* __restrict__ bsum, int n)
{
    __shared__ int sh[1024];
    const int tid = threadIdx.x;
    const int gid = blockIdx.x * 1024 + tid;
    int v = (gid < n) ? in[gid] : 0;
    sh[tid] = v;
    __syncthreads();
    #pragma unroll
    for (int d = 1; d < 1024; d <<= 1) {
        int t = (tid >= d) ? sh[tid - d] : 0;
        __syncthreads();
        sh[tid] += t;
        __syncthreads();
    }
    if (gid < n) out[gid] = sh[tid] - v;
    if (tid == 1023) bsum[blockIdx.x] = sh[1023];
}

__global__ __launch_bounds__(128)
void scan2_kernel(int* __restrict__ bsum, int nb)
{
    __shared__ int sh[128];
    const int tid = threadIdx.x;
    int v = (tid < nb) ? bsum[tid] : 0;
    sh[tid] = v;
    __syncthreads();
    #pragma unroll
    for (int d = 1; d < 128; d <<= 1) {
        int t = (tid >= d) ? sh[tid - d] : 0;
        __syncthreads();
        sh[tid] += t;
        __syncthreads();
    }
    if (tid < nb) bsum[tid] = sh[tid] - v;
}

__global__ __launch_bounds__(1024)
void scan3g_kernel(int* __restrict__ arr, const int* __restrict__ bsum, int n)
{
    const int gid = blockIdx.x * 1024 + threadIdx.x;
    if (gid < n) arr[gid] += bsum[blockIdx.x];
}

__global__ __launch_bounds__(256)
void p1b_scatter(const int* __restrict__ ei, const int* __restrict__ offs_T,
                 int2* __restrict__ ebuf)
{
    __shared__ int cur[NB];
    const int b = blockIdx.x, tid = threadIdx.x;
    for (int i = tid; i < NB; i += 256) cur[i] = offs_T[i * NCHUNK + b];
    __syncthreads();
    const int e0 = b * CHUNK;
    for (int e = e0 + tid; e < e0 + CHUNK; e += 256) {
        int s = ei[e], d = ei[NE + e];
        int pos = atomicAdd(&cur[d >> BSHIFT], 1);
        ebuf[pos] = make_int2(s, d);
    }
}

__global__ __launch_bounds__(512)
void p2_csr(const int2* __restrict__ ebuf, const int* __restrict__ offs_T,
            int* __restrict__ off, int* __restrict__ csr)
{
    __shared__ int degc[512];
    __shared__ int sh[512];
    const int k = blockIdx.x, tid = threadIdx.x;
    const int base = k << BSHIFT;
    const int bs = offs_T[k * NCHUNK];
    const int be = (k == NB - 1) ? NE : offs_T[(k + 1) * NCHUNK];
    degc[tid] = 0;
    __syncthreads();
    for (int e = bs + tid; e < be; e += 512)
        atomicAdd(&degc[ebuf[e].y - base], 1);
    __syncthreads();
    int v = degc[tid];
    sh[tid] = v;
    __syncthreads();
    #pragma unroll
    for (int d = 1; d < 512; d <<= 1) {
        int t = (tid >= d) ? sh[tid - d] : 0;
        __syncthreads();
        sh[tid] += t;
        __syncthreads();
    }
    const int excl = bs + sh[tid] - v;
    const int n = base + tid;
    if (n <= NN) off[n] = excl;
    degc[tid] = excl;
    __syncthreads();
    for (int e = bs + tid; e < be; e += 512) {
        int2 p = ebuf[e];
        int slot = atomicAdd(&degc[p.y - base], 1);
        csr[slot] = p.x;
    }
}

// ==================== aggregation: xeff = (h + sum_in h[src]) * 0.5 + h, packed hi|lo ====================
__global__ __launch_bounds__(256)
void aggregate_pack_kernel(const float* __restrict__ h, const int* __restrict__ off,
                           const int* __restrict__ csr, unsigned* __restrict__ xP, int nn)
{
    const int node = blockIdx.x * 4 + (threadIdx.x >> 6);
    if (node >= nn) return;
    const int lane = threadIdx.x & 63;
    const int s = off[node], e = off[node + 1];
    float2 acc = make_float2(0.f, 0.f);
    for (int base = s; base < e; base += 64) {
        const int cnt = min(64, e - base);
        int src_l = (base + lane < e) ? csr[base + lane] : 0;
        for (int jb = 0; jb < cnt; jb += 16) {
            float2 v[16];
            #pragma unroll
            for (int q = 0; q < 16; ++q) {
                int sq = __shfl(src_l, (jb + q) & 63);
                v[q] = reinterpret_cast<const float2*>(h + (size_t)sq * FEAT)[lane];
            }
            #pragma unroll
            for (int q = 0; q < 16; ++q) {
                if (jb + q < cnt) { acc.x += v[q].x; acc.y += v[q].y; }
            }
        }
    }
    float2 hv = reinterpret_cast<const float2*>(h + (size_t)node * FEAT)[lane];
    float ox = (hv.x + acc.x) * 0.5f + hv.x;
    float oy = (hv.y + acc.y) * 0.5f + hv.y;
    unsigned short hx = f2bf(ox), hy = f2bf(oy);
    unsigned wx = (unsigned)hx | ((unsigned)f2bf(ox - bf2f(hx)) << 16);
    unsigned wy = (unsigned)hy | ((unsigned)f2bf(oy - bf2f(hy)) << 16);
    uint2 pw = make_uint2(wx, wy);
    *reinterpret_cast<uint2*>(&xP[(size_t)node * FEAT + lane * 2]) = pw;
}

// ==================== MFMA split-bf16 GEMM v5: swapped operands (D = W·A^T), packed I/O ====================
// acc[nt][ct] tile: lane owns node = row0+nt*16+(lane&15), cols ct*16+(lane>>4)*4 .. +3.
__global__ __launch_bounds__(512, 4)
void gemm_mfma5_kernel(const unsigned* __restrict__ aP, const short* __restrict__ Wf,
                       const float* __restrict__ bias, float* __restrict__ outF,
                       unsigned* __restrict__ outP, int n_nodes)
{
    __shared__ short wlds[32768];   // 64 KB: [hi|lo] frag-major
    const int tid = threadIdx.x;
    const int lane = tid & 63;
    const int w = tid >> 6;
    const int lr = lane & 15;
    const int lq = lane >> 4;
    const int row0 = blockIdx.x * 256 + w * 32;

    // stage W: straight 64KB copy, lane-consecutive 16B chunks
    {
        const bf16x8* src = reinterpret_cast<const bf16x8*>(Wf);
        bf16x8* dst = reinterpret_cast<bf16x8*>(wlds);
        #pragma unroll
        for (int it = 0; it < 8; ++it)
            dst[it * 512 + tid] = src[it * 512 + tid];
    }

    const int n0 = row0 + lr;          // nt=0 node for this lane's fragment
    const int n1 = row0 + 16 + lr;     // nt=1
    const bool v0 = (n0 < n_nodes), v1 = (n1 < n_nodes);
    const size_t rb0 = (size_t)n0 * FEAT + lq * 8;
    const size_t rb1 = (size_t)n1 * FEAT + lq * 8;
    u32x4 zz = {};

    // kc=0 packed A loads issued before the barrier
    u32x4 pa0a = v0 ? *reinterpret_cast<const u32x4*>(&aP[rb0])     : zz;
    u32x4 pa0b = v0 ? *reinterpret_cast<const u32x4*>(&aP[rb0 + 4]) : zz;
    u32x4 pa1a = v1 ? *reinterpret_cast<const u32x4*>(&aP[rb1])     : zz;
    u32x4 pa1b = v1 ? *reinterpret_cast<const u32x4*>(&aP[rb1 + 4]) : zz;
    __syncthreads();

    f32x4 acc[2][8] = {};
    bf16x8 ah0, al0, ah1, al1;
    unpack8(pa0a, pa0b, ah0, al0);
    unpack8(pa1a, pa1b, ah1, al1);

    #pragma unroll
    for (int kc = 0; kc < 4; ++kc) {
        u32x4 n0a = zz, n0b = zz, n1a = zz, n1b = zz;
        if (kc < 3) {
            const int ko = (kc + 1) * 32;
            n0a = v0 ? *reinterpret_cast<const u32x4*>(&aP[rb0 + ko])     : zz;
            n0b = v0 ? *reinterpret_cast<const u32x4*>(&aP[rb0 + ko + 4]) : zz;
            n1a = v1 ? *reinterpret_cast<const u32x4*>(&aP[rb1 + ko])     : zz;
            n1b = v1 ? *reinterpret_cast<const u32x4*>(&aP[rb1 + ko + 4]) : zz;
        }
        #pragma unroll
        for (int ct = 0; ct < 8; ++ct) {
            const int ra = (kc * 8 + ct) * 512 + lane * 8;
            bf16x8 bh = *reinterpret_cast<const bf16x8*>(&wlds[ra]);
            bf16x8 bl = *reinterpret_cast<const bf16x8*>(&wlds[16384 + ra]);
            // swapped operands: D = W · A^T  (W-frag first)
            acc[0][ct] = __builtin_amdgcn_mfma_f32_16x16x32_bf16(bh, ah0, acc[0][ct], 0, 0, 0);
            acc[0][ct] = __builtin_amdgcn_mfma_f32_16x16x32_bf16(bh, al0, acc[0][ct], 0, 0, 0);
            acc[0][ct] = __builtin_amdgcn_mfma_f32_16x16x32_bf16(bl, ah0, acc[0][ct], 0, 0, 0);
            acc[1][ct] = __builtin_amdgcn_mfma_f32_16x16x32_bf16(bh, ah1, acc[1][ct], 0, 0, 0);
            acc[1][ct] = __builtin_amdgcn_mfma_f32_16x16x32_bf16(bh, al1, acc[1][ct], 0, 0, 0);
            acc[1][ct] = __builtin_amdgcn_mfma_f32_16x16x32_bf16(bl, ah1, acc[1][ct], 0, 0, 0);
        }
        if (kc < 3) {
            unpack8(n0a, n0b, ah0, al0);
            unpack8(n1a, n1b, ah1, al1);
        }
    }

    // epilogue: lane owns node = row0 + nt*16 + (lane&15); cols c0 = ct*16 + lq*4 .. +3
    #pragma unroll
    for (int nt = 0; nt < 2; ++nt) {
        const int n = row0 + nt * 16 + lr;
        if (n >= n_nodes) continue;
        #pragma unroll
        for (int ct = 0; ct < 8; ++ct) {
            const int c0 = ct * 16 + lq * 4;
            float4 bv = *reinterpret_cast<const float4*>(&bias[c0]);
            f32x4 a = acc[nt][ct];
            float e0 = fmaxf(a[0] + bv.x, 0.f);
            float e1 = fmaxf(a[1] + bv.y, 0.f);
            float e2 = fmaxf(a[2] + bv.z, 0.f);
            float e3 = fmaxf(a[3] + bv.w, 0.f);
            if (outF) {
                float4 o = make_float4(e0, e1, e2, e3);
                *reinterpret_cast<float4*>(&outF[(size_t)n * FEAT + c0]) = o;
            } else {
                unsigned short h0 = f2bf(e0), h1 = f2bf(e1), h2 = f2bf(e2), h3 = f2bf(e3);
                u32x4 pw;
                pw.x = (unsigned)h0 | ((unsigned)f2bf(e0 - bf2f(h0)) << 16);
                pw.y = (unsigned)h1 | ((unsigned)f2bf(e1 - bf2f(h1)) << 16);
                pw.z = (unsigned)h2 | ((unsigned)f2bf(e2 - bf2f(h2)) << 16);
                pw.w = (unsigned)h3 | ((unsigned)f2bf(e3 - bf2f(h3)) << 16);
                *reinterpret_cast<u32x4*>(&outP[(size_t)n * FEAT + c0]) = pw;
            }
        }
    }
}

// ==================== pooling ====================
__global__ __launch_bounds__(512)
void pool_kernel(const float* __restrict__ y, const int* __restrict__ batch,
                 float* __restrict__ out, int n_nodes, int layer)
{
    const int g = blockIdx.x;
    int lo = 0, hi = n_nodes;
    while (lo < hi) { int mid = (lo + hi) >> 1; if (batch[mid] < g) lo = mid + 1; else hi = mid; }
    const int start = lo;
    hi = n_nodes;
    while (lo < hi) { int mid = (lo + hi) >> 1; if (batch[mid] < g + 1) lo = mid + 1; else hi = mid; }
    const int end = lo;

    const int tid = threadIdx.x;
    const int f = tid & 127;
    const int q = tid >> 7;
    float sum = 0.f;
    for (int n = start + q; n < end; n += 4)
        sum += y[(size_t)n * FEAT + f];

    __shared__ float red[512];
    red[tid] = sum;
    __syncthreads();
    if (tid < 128)
        out[g * (3 * FEAT) + layer * FEAT + tid]
            = red[tid] + red[tid + 128] + red[tid + 256] + red[tid + 384];
}

// ==================== fallback path kernels (ws too small) ====================
__global__ __launch_bounds__(256)
void scatter_kernel(const float* __restrict__ h, const int* __restrict__ ei,
                    float* __restrict__ agg, int n_edges)
{
    int e = blockIdx.x * 4 + (threadIdx.x >> 6);
    if (e >= n_edges) return;
    int lane = threadIdx.x & 63;
    int s = ei[e];
    int d = ei[n_edges + e];
    float2 v = reinterpret_cast<const float2*>(h + (size_t)s * FEAT)[lane];
    float* ap = agg + (size_t)d * FEAT + lane * 2;
    atomicAdd(ap, v.x);
    atomicAdd(ap + 1, v.y);
}

__global__ __launch_bounds__(256)
void combine_kernel(const float* __restrict__ h, float* __restrict__ agg_xeff, size_t n4)
{
    size_t i = (size_t)blockIdx.x * 256 + threadIdx.x;
    if (i >= n4) return;
    float4 a = reinterpret_cast<const float4*>(h)[i];
    float4 g = reinterpret_cast<float4*>(agg_xeff)[i];
    float4 o;
    o.x = (a.x + g.x) * 0.5f + a.x;
    o.y = (a.y + g.y) * 0.5f + a.y;
    o.z = (a.z + g.z) * 0.5f + a.z;
    o.w = (a.w + g.w) * 0.5f + a.w;
    reinterpret_cast<float4*>(agg_xeff)[i] = o;
}

__global__ __launch_bounds__(256, 2)
void gemm_relu_kernel(const float* __restrict__ A, const float* __restrict__ W,
                      const float* __restrict__ bias, float* __restrict__ out, int n_nodes)
{
    __shared__ float xt[64][128];
    __shared__ float wt[64][128];
    const int tid = threadIdx.x;
    const int row0 = blockIdx.x * 128;
    const int r  = tid >> 1;
    const int ks = (tid & 1) << 5;
    const int tn = (tid >> 4) << 3;
    const int to = (tid & 15) << 3;
    float acc[8][8] = {};

    for (int c = 0; c < 2; ++c) {
        const int k0 = c * 64;
        {
            const float4* wrow = reinterpret_cast<const float4*>(W + r * FEAT + k0 + ks);
            #pragma unroll
            for (int i = 0; i < 8; ++i) {
                float4 w4 = wrow[i];
                int kk = ks + i * 4;
                wt[kk + 0][r] = w4.x; wt[kk + 1][r] = w4.y;
                wt[kk + 2][r] = w4.z; wt[kk + 3][r] = w4.w;
            }
        }
        {
            const int n = row0 + r;
            if (n < n_nodes) {
                const float4* ar = reinterpret_cast<const float4*>(A + (size_t)n * FEAT + k0 + ks);
                #pragma unroll
                for (int i = 0; i < 8; ++i) {
                    float4 a4 = ar[i];
                    int kk = ks + i * 4;
                    xt[kk + 0][r] = a4.x; xt[kk + 1][r] = a4.y;
                    xt[kk + 2][r] = a4.z; xt[kk + 3][r] = a4.w;
                }
            } else {
                #pragma unroll
                for (int i = 0; i < 8; ++i) {
                    int kk = ks + i * 4;
                    xt[kk + 0][r] = 0.f; xt[kk + 1][r] = 0.f;
                    xt[kk + 2][r] = 0.f; xt[kk + 3][r] = 0.f;
                }
            }
        }
        __syncthreads();
        #pragma unroll 4
        for (int k = 0; k < 64; ++k) {
            float4 x0 = *reinterpret_cast<const float4*>(&xt[k][tn]);
            float4 x1 = *reinterpret_cast<const float4*>(&xt[k][tn + 4]);
            float4 w0 = *reinterpret_cast<const float4*>(&wt[k][to]);
            float4 w1 = *reinterpret_cast<const float4*>(&wt[k][to + 4]);
            float xv[8] = {x0.x, x0.y, x0.z, x0.w, x1.x, x1.y, x1.z, x1.w};
            float wv[8] = {w0.x, w0.y, w0.z, w0.w, w1.x, w1.y, w1.z, w1.w};
            #pragma unroll
            for (int i = 0; i < 8; ++i)
                #pragma unroll
                for (int j = 0; j < 8; ++j)
                    acc[i][j] = fmaf(xv[i], wv[j], acc[i][j]);
        }
        __syncthreads();
    }

    float bv[8];
    #pragma unroll
    for (int j = 0; j < 8; ++j) bv[j] = bias[to + j];
    #pragma unroll
    for (int i = 0; i < 8; ++i) {
        int n = row0 + tn + i;
        if (n >= n_nodes) break;
        float4 o0, o1;
        o0.x = fmaxf(acc[i][0] + bv[0], 0.f);
        o0.y = fmaxf(acc[i][1] + bv[1], 0.f);
        o0.z = fmaxf(acc[i][2] + bv[2], 0.f);
        o0.w = fmaxf(acc[i][3] + bv[3], 0.f);
        o1.x = fmaxf(acc[i][4] + bv[4], 0.f);
        o1.y = fmaxf(acc[i][5] + bv[5], 0.f);
        o1.z = fmaxf(acc[i][6] + bv[6], 0.f);
        o1.w = fmaxf(acc[i][7] + bv[7], 0.f);
        float* op = out + (size_t)n * FEAT + to;
        *reinterpret_cast<float4*>(op) = o0;
        *reinterpret_cast<float4*>(op + 4) = o1;
    }
}

extern "C" void kernel_launch(void* const* d_in, const int* in_sizes, int n_in,
                              void* d_out, int out_size, void* d_ws, size_t ws_size,
                              hipStream_t stream)
{
    const float* x     = (const float*)d_in[0];
    const int*   ei    = (const int*)d_in[1];
    const int*   batch = (const int*)d_in[2];
    const float* W1[3] = {(const float*)d_in[4], (const float*)d_in[8],  (const float*)d_in[12]};
    const float* b1[3] = {(const float*)d_in[5], (const float*)d_in[9],  (const float*)d_in[13]};
    const float* W2[3] = {(const float*)d_in[6], (const float*)d_in[10], (const float*)d_in[14]};
    const float* b2[3] = {(const float*)d_in[7], (const float*)d_in[11], (const float*)d_in[15]};

    const size_t nf = (size_t)NN * FEAT;
    float* outp = (float*)d_out;
    const int gemm_grid = (NN + 255) / 256;          // 391
    const int M = NB * NCHUNK;                       // 78400
    const int scanM_blocks = (M + 1023) / 1024;      // 77
    const int WN = FEAT * FEAT;                      // 16384

    const size_t need_full = 3 * nf * 4 + (size_t)(NN + 1 + NE) * 4 + (size_t)12 * WN * 2;

    if (ws_size >= need_full) {
        unsigned* xeffP = (unsigned*)d_ws;       // nf dwords (hi|lo packed)
        unsigned* h1P   = xeffP + nf;            // nf dwords
        float* bufC     = (float*)(h1P + nf);    // nf floats
        int* off        = (int*)(bufC + nf);     // NN+1
        int* csr        = off + (NN + 1);        // NE
        short* wbase    = (short*)(csr + NE);    // 12 * WN shorts
        short* wf[6];
        for (int i = 0; i < 6; ++i) wf[i] = wbase + (size_t)i * 2 * WN;
        // build transients aliased into plane space (written only after build)
        int* cnt_T  = (int*)xeffP;               // M
        int* offs_T = cnt_T + M;                 // M
        int* bsum   = offs_T + M;                // 77
        int2* ebuf  = (int2*)h1P;                // NE pairs (12.8 MB < 51.2 MB)

        const float* Ws[6] = {W1[0], W2[0], W1[1], W2[1], W1[2], W2[2]};
        for (int i = 0; i < 6; ++i)
            wsplit_frag_kernel<<<WN / 256, 256, 0, stream>>>(Ws[i], wf[i]);

        p1a_count<<<NCHUNK, 256, 0, stream>>>(ei, cnt_T);
        scan1_kernel<<<scanM_blocks, 1024, 0, stream>>>(cnt_T, offs_T, bsum, M);
        scan2_kernel<<<1, 128, 0, stream>>>(bsum, scanM_blocks);
        scan3g_kernel<<<scanM_blocks, 1024, 0, stream>>>(offs_T, bsum, M);
        p1b_scatter<<<NCHUNK, 256, 0, stream>>>(ei, offs_T, ebuf);
        p2_csr<<<NB, 512, 0, stream>>>(ebuf, offs_T, off, csr);

        const float* h = x;
        for (int l = 0; l < 3; ++l) {
            aggregate_pack_kernel<<<(NN + 3) / 4, 256, 0, stream>>>(h, off, csr, xeffP, NN);
            gemm_mfma5_kernel<<<gemm_grid, 512, 0, stream>>>(xeffP, wf[2 * l], b1[l],
                                                             nullptr, h1P, NN);
            gemm_mfma5_kernel<<<gemm_grid, 512, 0, stream>>>(h1P, wf[2 * l + 1], b2[l],
                                                             bufC, nullptr, NN);
            pool_kernel<<<NGRAPH, 512, 0, stream>>>(bufC, batch, outp, NN, l);
            h = bufC;
        }
    } else if (ws_size >= 3 * nf * 4) {
        float* bufA = (float*)d_ws;
        float* bufB = bufA + nf;
        float* bufC = bufB + nf;
        const int gg = (NN + 127) / 128;
        const float* h = x;
        for (int l = 0; l < 3; ++l) {
            hipMemsetAsync(bufA, 0, nf * 4, stream);
            scatter_kernel<<<(NE + 3) / 4, 256, 0, stream>>>(h, ei, bufA, NE);
            combine_kernel<<<(int)((nf / 4 + 255) / 256), 256, 0, stream>>>(h, bufA, nf / 4);
            gemm_relu_kernel<<<gg, 256, 0, stream>>>(bufA, W1[l], b1[l], bufB, NN);
            gemm_relu_kernel<<<gg, 256, 0, stream>>>(bufB, W2[l], b2[l], bufC, NN);
            pool_kernel<<<NGRAPH, 512, 0, stream>>>(bufC, batch, outp, NN, l);
            h = bufC;
        }
    }
}

// Round 13
// 692.558 us; speedup vs baseline: 1.3363x; 1.0422x over previous
//
#include <hip/hip_runtime.h>

#define NN 100000
#define NE 1600000
#define FEAT 128
#define NGRAPH 128
#define BSHIFT 9
#define NB 196          // ceil(NN / 512)
#define NCHUNK 400
#define CHUNK 4000      // NE / NCHUNK exactly

typedef __attribute__((ext_vector_type(8))) short bf16x8;
typedef __attribute__((ext_vector_type(4))) float f32x4;
typedef __attribute__((ext_vector_type(4))) unsigned u32x4;

union U4 { u32x4 u; bf16x8 v; };

__device__ __forceinline__ unsigned short f2bf(float f) {
    unsigned u = __float_as_uint(f);
    return (unsigned short)((u + 0x7fffu + ((u >> 16) & 1u)) >> 16);  // RNE
}
__device__ __forceinline__ float bf2f(unsigned short h) {
    return __uint_as_float(((unsigned)h) << 16);
}
__device__ __forceinline__ unsigned packbf(float f) {
    unsigned short h = f2bf(f);
    return (unsigned)h | ((unsigned)f2bf(f - bf2f(h)) << 16);
}
// two packed (hi|lo<<16) dwords -> {hi-pair dword, lo-pair dword}
__device__ __forceinline__ uint2 unpack2(unsigned p0, unsigned p1) {
    return make_uint2((p0 & 0xffffu) | (p1 << 16), (p0 >> 16) | (p1 & 0xffff0000u));
}
// unpack 8 packed elems into hi-plane / lo-plane bf16x8
__device__ __forceinline__ void unpack8(u32x4 a, u32x4 b, bf16x8& hv, bf16x8& lv) {
    uint2 r0 = unpack2(a.x, a.y), r1 = unpack2(a.z, a.w);
    uint2 r2 = unpack2(b.x, b.y), r3 = unpack2(b.z, b.w);
    U4 h, l;
    h.u = (u32x4){r0.x, r1.x, r2.x, r3.x};
    l.u = (u32x4){r0.y, r1.y, r2.y, r3.y};
    hv = h.v; lv = l.v;
}

// ==================== W hi/lo split -> fragment-major layout ====================
__global__ __launch_bounds__(256)
void wsplit_frag_kernel(const float* __restrict__ W, short* __restrict__ Wf)
{
    int i = blockIdx.x * 256 + threadIdx.x;   // 16384 elements
    int o = i >> 7, k = i & 127;
    float f = W[i];
    unsigned short h = f2bf(f);
    short lo = (short)f2bf(f - bf2f(h));
    int ct = o >> 4, lr = o & 15, kc = k >> 5, q = (k >> 3) & 3, j = k & 7;
    int idx = (kc * 8 + ct) * 512 + ((q << 4) | lr) * 8 + j;
    Wf[idx] = (short)h;
    Wf[16384 + idx] = lo;
}

// ==================== radix-partition CSR build ====================
__global__ __launch_bounds__(256)
void p1a_count(const int* __restrict__ ei, int* __restrict__ cnt_T)
{
    __shared__ int hist[NB];
    const int b = blockIdx.x, tid = threadIdx.x;
    for (int i = tid; i < NB; i += 256) hist[i] = 0;
    __syncthreads();
    const int e0 = b * CHUNK;
    for (int e = e0 + tid; e < e0 + CHUNK; e += 256)
        atomicAdd(&hist[ei[NE + e] >> BSHIFT], 1);
    __syncthreads();
    for (int k = tid; k < NB; k += 256) cnt_T[k * NCHUNK + b] = hist[k];
}

__global__ __launch_bounds__(1024)
void scan1_kernel(const int* __restrict__ in, int* __restrict__ out,
                  int* __restrict__ bsum, int n)
{
    __shared__ int sh[1024];
    const int tid = threadIdx.x;
    const int gid = blockIdx.x * 1024 + tid;
    int v = (gid < n) ? in[gid] : 0;
    sh[tid] = v;
    __syncthreads();
    #pragma unroll
    for (int d = 1; d < 1024; d <<= 1) {
        int t = (tid >= d) ? sh[tid - d] : 0;
        __syncthreads();
        sh[tid] += t;
        __syncthreads();
    }
    if (gid < n) out[gid] = sh[tid] - v;
    if (tid == 1023) bsum[blockIdx.x] = sh[1023];
}

__global__ __launch_bounds__(128)
void scan2_kernel(int* __restrict__ bsum, int nb)
{
    __shared__ int sh[128];
    const int tid = threadIdx.x;
    int v = (tid < nb) ? bsum[tid] : 0;
    sh[tid] = v;
    __syncthreads();
    #pragma unroll
    for (int d = 1; d < 128; d <<= 1) {
        int t = (tid >= d) ? sh[tid - d] : 0;
        __syncthreads();
        sh[tid] += t;
        __syncthreads();
    }
    if (tid < nb) bsum[tid] = sh[tid] - v;
}

__global__ __launch_bounds__(1024)
void scan3g_kernel(int* __restrict__ arr, const int* __restrict__ bsum, int n)
{
    const int gid = blockIdx.x * 1024 + threadIdx.x;
    if (gid < n) arr[gid] += bsum[blockIdx.x];
}

__global__ __launch_bounds__(256)
void p1b_scatter(const int* __restrict__ ei, const int* __restrict__ offs_T,
                 int2* __restrict__ ebuf)
{
    __shared__ int cur[NB];
    const int b = blockIdx.x, tid = threadIdx.x;
    for (int i = tid; i < NB; i += 256) cur[i] = offs_T[i * NCHUNK + b];
    __syncthreads();
    const int e0 = b * CHUNK;
    for (int e = e0 + tid; e < e0 + CHUNK; e += 256) {
        int s = ei[e], d = ei[NE + e];
        int pos = atomicAdd(&cur[d >> BSHIFT], 1);
        ebuf[pos] = make_int2(s, d);
    }
}

__global__ __launch_bounds__(512)
void p2_csr(const int2* __restrict__ ebuf, const int* __restrict__ offs_T,
            int* __restrict__ off, int* __restrict__ csr)
{
    __shared__ int degc[512];
    __shared__ int sh[512];
    const int k = blockIdx.x, tid = threadIdx.x;
    const int base = k << BSHIFT;
    const int bs = offs_T[k * NCHUNK];
    const int be = (k == NB - 1) ? NE : offs_T[(k + 1) * NCHUNK];
    degc[tid] = 0;
    __syncthreads();
    for (int e = bs + tid; e < be; e += 512)
        atomicAdd(&degc[ebuf[e].y - base], 1);
    __syncthreads();
    int v = degc[tid];
    sh[tid] = v;
    __syncthreads();
    #pragma unroll
    for (int d = 1; d < 512; d <<= 1) {
        int t = (tid >= d) ? sh[tid - d] : 0;
        __syncthreads();
        sh[tid] += t;
        __syncthreads();
    }
    const int excl = bs + sh[tid] - v;
    const int n = base + tid;
    if (n <= NN) off[n] = excl;
    degc[tid] = excl;
    __syncthreads();
    for (int e = bs + tid; e < be; e += 512) {
        int2 p = ebuf[e];
        int slot = atomicAdd(&degc[p.y - base], 1);
        csr[slot] = p.x;
    }
}

// ==================== aggregation: xeff = (h + sum_in h[src]) * 0.5 + h, packed hi|lo ====================
__global__ __launch_bounds__(256)
void aggregate_pack_kernel(const float* __restrict__ h, const int* __restrict__ off,
                           const int* __restrict__ csr, unsigned* __restrict__ xP, int nn)
{
    const int node = blockIdx.x * 4 + (threadIdx.x >> 6);
    if (node >= nn) return;
    const int lane = threadIdx.x & 63;
    const int s = off[node], e = off[node + 1];
    float2 acc = make_float2(0.f, 0.f);
    for (int base = s; base < e; base += 64) {
        const int cnt = min(64, e - base);
        int src_l = (base + lane < e) ? csr[base + lane] : 0;
        for (int jb = 0; jb < cnt; jb += 16) {
            float2 v[16];
            #pragma unroll
            for (int q = 0; q < 16; ++q) {
                int sq = __shfl(src_l, (jb + q) & 63);
                v[q] = reinterpret_cast<const float2*>(h + (size_t)sq * FEAT)[lane];
            }
            #pragma unroll
            for (int q = 0; q < 16; ++q) {
                if (jb + q < cnt) { acc.x += v[q].x; acc.y += v[q].y; }
            }
        }
    }
    float2 hv = reinterpret_cast<const float2*>(h + (size_t)node * FEAT)[lane];
    float ox = (hv.x + acc.x) * 0.5f + hv.x;
    float oy = (hv.y + acc.y) * 0.5f + hv.y;
    uint2 pw = make_uint2(packbf(ox), packbf(oy));
    *reinterpret_cast<uint2*>(&xP[(size_t)node * FEAT + lane * 2]) = pw;
}

// ==================== fused layer: out = relu(relu(xeff@W1^T+b1)@W2^T+b2) ====================
// 512 threads = 8 waves x 16 rows = 128 rows/block. One row per lane.
// Swapped-operand MFMA (D = W · A^T): lane (lr,lq) holds D[own row][ct*16+lq*4+j].
// W1 staged in 64KB LDS, then overwritten by W2. h1 kept packed in 32 VGPR;
// redistributed to B-fragment layout via 4-lane shfl (static reg indices only).
__global__ __launch_bounds__(512, 4)
void layer_fused_kernel(const unsigned* __restrict__ aP, const short* __restrict__ Wf1,
                        const short* __restrict__ Wf2, const float* __restrict__ b1,
                        const float* __restrict__ b2, float* __restrict__ outC, int n_nodes)
{
    __shared__ short wlds[32768];   // 64 KB frag-major [hi|lo]
    const int tid = threadIdx.x;
    const int lane = tid & 63;
    const int w = tid >> 6;
    const int lr = lane & 15;
    const int lq = lane >> 4;
    const int n0 = blockIdx.x * 128 + w * 16 + lr;
    const bool v0 = (n0 < n_nodes);
    const size_t rb0 = (size_t)n0 * FEAT + lq * 8;
    u32x4 zz = {};

    // ---- stage W1 ----
    {
        const bf16x8* src = reinterpret_cast<const bf16x8*>(Wf1);
        bf16x8* dst = reinterpret_cast<bf16x8*>(wlds);
        #pragma unroll
        for (int it = 0; it < 8; ++it)
            dst[it * 512 + tid] = src[it * 512 + tid];
    }
    // prologue A load (kc=0) before barrier
    u32x4 paa = v0 ? *reinterpret_cast<const u32x4*>(&aP[rb0])     : zz;
    u32x4 pab = v0 ? *reinterpret_cast<const u32x4*>(&aP[rb0 + 4]) : zz;
    __syncthreads();

    // ---- GEMM1 ----
    f32x4 acc[8] = {};
    bf16x8 ah, al;
    unpack8(paa, pab, ah, al);
    #pragma unroll
    for (int kc = 0; kc < 4; ++kc) {
        u32x4 na = zz, nb = zz;
        if (kc < 3) {
            const int ko = (kc + 1) * 32;
            na = v0 ? *reinterpret_cast<const u32x4*>(&aP[rb0 + ko])     : zz;
            nb = v0 ? *reinterpret_cast<const u32x4*>(&aP[rb0 + ko + 4]) : zz;
        }
        #pragma unroll
        for (int ct = 0; ct < 8; ++ct) {
            const int ra = (kc * 8 + ct) * 512 + lane * 8;
            bf16x8 bh = *reinterpret_cast<const bf16x8*>(&wlds[ra]);
            bf16x8 bl = *reinterpret_cast<const bf16x8*>(&wlds[16384 + ra]);
            acc[ct] = __builtin_amdgcn_mfma_f32_16x16x32_bf16(bh, ah, acc[ct], 0, 0, 0);
            acc[ct] = __builtin_amdgcn_mfma_f32_16x16x32_bf16(bh, al, acc[ct], 0, 0, 0);
            acc[ct] = __builtin_amdgcn_mfma_f32_16x16x32_bf16(bl, ah, acc[ct], 0, 0, 0);
        }
        if (kc < 3) unpack8(na, nb, ah, al);
    }

    // ---- h1 = relu(acc + b1), packed in regs ----
    unsigned h1p[32];
    #pragma unroll
    for (int ct = 0; ct < 8; ++ct) {
        const int c0 = ct * 16 + lq * 4;
        float4 bv = *reinterpret_cast<const float4*>(&b1[c0]);
        h1p[ct * 4 + 0] = packbf(fmaxf(acc[ct][0] + bv.x, 0.f));
        h1p[ct * 4 + 1] = packbf(fmaxf(acc[ct][1] + bv.y, 0.f));
        h1p[ct * 4 + 2] = packbf(fmaxf(acc[ct][2] + bv.z, 0.f));
        h1p[ct * 4 + 3] = packbf(fmaxf(acc[ct][3] + bv.w, 0.f));
    }

    // ---- stage W2 over W1 ----
    __syncthreads();   // all W1 LDS reads complete
    {
        const bf16x8* src = reinterpret_cast<const bf16x8*>(Wf2);
        bf16x8* dst = reinterpret_cast<bf16x8*>(wlds);
        #pragma unroll
        for (int it = 0; it < 8; ++it)
            dst[it * 512 + tid] = src[it * 512 + tid];
    }
    __syncthreads();

    // ---- GEMM2: B-frag from h1p via 4-lane shfl ----
    f32x4 acc2[8] = {};
    const int aown = (lq & 1) * 2;
    const bool hi_t = (lq & 2) != 0;
    #pragma unroll
    for (int kc = 0; kc < 4; ++kc) {
        unsigned pd[8];
        #pragma unroll
        for (int m = 0; m < 4; ++m) {
            unsigned vA = h1p[(2 * kc) * 4 + m];       // tile 2kc
            unsigned vB = h1p[(2 * kc + 1) * 4 + m];   // tile 2kc+1
            unsigned sA0 = __shfl(vA, lr + 16 * aown);
            unsigned sB0 = __shfl(vB, lr + 16 * aown);
            unsigned sA1 = __shfl(vA, lr + 16 * (aown + 1));
            unsigned sB1 = __shfl(vB, lr + 16 * (aown + 1));
            pd[m]     = hi_t ? sB0 : sA0;
            pd[4 + m] = hi_t ? sB1 : sA1;
        }
        u32x4 qa = {pd[0], pd[1], pd[2], pd[3]};
        u32x4 qb = {pd[4], pd[5], pd[6], pd[7]};
        bf16x8 hh, hl;
        unpack8(qa, qb, hh, hl);
        #pragma unroll
        for (int ct = 0; ct < 8; ++ct) {
            const int ra = (kc * 8 + ct) * 512 + lane * 8;
            bf16x8 bh = *reinterpret_cast<const bf16x8*>(&wlds[ra]);
            bf16x8 bl = *reinterpret_cast<const bf16x8*>(&wlds[16384 + ra]);
            acc2[ct] = __builtin_amdgcn_mfma_f32_16x16x32_bf16(bh, hh, acc2[ct], 0, 0, 0);
            acc2[ct] = __builtin_amdgcn_mfma_f32_16x16x32_bf16(bh, hl, acc2[ct], 0, 0, 0);
            acc2[ct] = __builtin_amdgcn_mfma_f32_16x16x32_bf16(bl, hh, acc2[ct], 0, 0, 0);
        }
    }

    // ---- epilogue: fp32 out ----
    if (v0) {
        #pragma unroll
        for (int ct = 0; ct < 8; ++ct) {
            const int c0 = ct * 16 + lq * 4;
            float4 bv = *reinterpret_cast<const float4*>(&b2[c0]);
            float4 o;
            o.x = fmaxf(acc2[ct][0] + bv.x, 0.f);
            o.y = fmaxf(acc2[ct][1] + bv.y, 0.f);
            o.z = fmaxf(acc2[ct][2] + bv.z, 0.f);
            o.w = fmaxf(acc2[ct][3] + bv.w, 0.f);
            *reinterpret_cast<float4*>(&outC[(size_t)n0 * FEAT + c0]) = o;
        }
    }
}

// ==================== pooling ====================
__global__ __launch_bounds__(512)
void pool_kernel(const float* __restrict__ y, const int* __restrict__ batch,
                 float* __restrict__ out, int n_nodes, int layer)
{
    const int g = blockIdx.x;
    int lo = 0, hi = n_nodes;
    while (lo < hi) { int mid = (lo + hi) >> 1; if (batch[mid] < g) lo = mid + 1; else hi = mid; }
    const int start = lo;
    hi = n_nodes;
    while (lo < hi) { int mid = (lo + hi) >> 1; if (batch[mid] < g + 1) lo = mid + 1; else hi = mid; }
    const int end = lo;

    const int tid = threadIdx.x;
    const int f = tid & 127;
    const int q = tid >> 7;
    float sum = 0.f;
    for (int n = start + q; n < end; n += 4)
        sum += y[(size_t)n * FEAT + f];

    __shared__ float red[512];
    red[tid] = sum;
    __syncthreads();
    if (tid < 128)
        out[g * (3 * FEAT) + layer * FEAT + tid]
            = red[tid] + red[tid + 128] + red[tid + 256] + red[tid + 384];
}

// ==================== fallback path kernels (ws too small) ====================
__global__ __launch_bounds__(256)
void scatter_kernel(const float* __restrict__ h, const int* __restrict__ ei,
                    float* __restrict__ agg, int n_edges)
{
    int e = blockIdx.x * 4 + (threadIdx.x >> 6);
    if (e >= n_edges) return;
    int lane = threadIdx.x & 63;
    int s = ei[e];
    int d = ei[n_edges + e];
    float2 v = reinterpret_cast<const float2*>(h + (size_t)s * FEAT)[lane];
    float* ap = agg + (size_t)d * FEAT + lane * 2;
    atomicAdd(ap, v.x);
    atomicAdd(ap + 1, v.y);
}

__global__ __launch_bounds__(256)
void combine_kernel(const float* __restrict__ h, float* __restrict__ agg_xeff, size_t n4)
{
    size_t i = (size_t)blockIdx.x * 256 + threadIdx.x;
    if (i >= n4) return;
    float4 a = reinterpret_cast<const float4*>(h)[i];
    float4 g = reinterpret_cast<float4*>(agg_xeff)[i];
    float4 o;
    o.x = (a.x + g.x) * 0.5f + a.x;
    o.y = (a.y + g.y) * 0.5f + a.y;
    o.z = (a.z + g.z) * 0.5f + a.z;
    o.w = (a.w + g.w) * 0.5f + a.w;
    reinterpret_cast<float4*>(agg_xeff)[i] = o;
}

__global__ __launch_bounds__(256, 2)
void gemm_relu_kernel(const float* __restrict__ A, const float* __restrict__ W,
                      const float* __restrict__ bias, float* __restrict__ out, int n_nodes)
{
    __shared__ float xt[64][128];
    __shared__ float wt[64][128];
    const int tid = threadIdx.x;
    const int row0 = blockIdx.x * 128;
    const int r  = tid >> 1;
    const int ks = (tid & 1) << 5;
    const int tn = (tid >> 4) << 3;
    const int to = (tid & 15) << 3;
    float acc[8][8] = {};

    for (int c = 0; c < 2; ++c) {
        const int k0 = c * 64;
        {
            const float4* wrow = reinterpret_cast<const float4*>(W + r * FEAT + k0 + ks);
            #pragma unroll
            for (int i = 0; i < 8; ++i) {
                float4 w4 = wrow[i];
                int kk = ks + i * 4;
                wt[kk + 0][r] = w4.x; wt[kk + 1][r] = w4.y;
                wt[kk + 2][r] = w4.z; wt[kk + 3][r] = w4.w;
            }
        }
        {
            const int n = row0 + r;
            if (n < n_nodes) {
                const float4* ar = reinterpret_cast<const float4*>(A + (size_t)n * FEAT + k0 + ks);
                #pragma unroll
                for (int i = 0; i < 8; ++i) {
                    float4 a4 = ar[i];
                    int kk = ks + i * 4;
                    xt[kk + 0][r] = a4.x; xt[kk + 1][r] = a4.y;
                    xt[kk + 2][r] = a4.z; xt[kk + 3][r] = a4.w;
                }
            } else {
                #pragma unroll
                for (int i = 0; i < 8; ++i) {
                    int kk = ks + i * 4;
                    xt[kk + 0][r] = 0.f; xt[kk + 1][r] = 0.f;
                    xt[kk + 2][r] = 0.f; xt[kk + 3][r] = 0.f;
                }
            }
        }
        __syncthreads();
        #pragma unroll 4
        for (int k = 0; k < 64; ++k) {
            float4 x0 = *reinterpret_cast<const float4*>(&xt[k][tn]);
            float4 x1 = *reinterpret_cast<const float4*>(&xt[k][tn + 4]);
            float4 w0 = *reinterpret_cast<const float4*>(&wt[k][to]);
            float4 w1 = *reinterpret_cast<const float4*>(&wt[k][to + 4]);
            float xv[8] = {x0.x, x0.y, x0.z, x0.w, x1.x, x1.y, x1.z, x1.w};
            float wv[8] = {w0.x, w0.y, w0.z, w0.w, w1.x, w1.y, w1.z, w1.w};
            #pragma unroll
            for (int i = 0; i < 8; ++i)
                #pragma unroll
                for (int j = 0; j < 8; ++j)
                    acc[i][j] = fmaf(xv[i], wv[j], acc[i][j]);
        }
        __syncthreads();
    }

    float bv[8];
    #pragma unroll
    for (int j = 0; j < 8; ++j) bv[j] = bias[to + j];
    #pragma unroll
    for (int i = 0; i < 8; ++i) {
        int n = row0 + tn + i;
        if (n >= n_nodes) break;
        float4 o0, o1;
        o0.x = fmaxf(acc[i][0] + bv[0], 0.f);
        o0.y = fmaxf(acc[i][1] + bv[1], 0.f);
        o0.z = fmaxf(acc[i][2] + bv[2], 0.f);
        o0.w = fmaxf(acc[i][3] + bv[3], 0.f);
        o1.x = fmaxf(acc[i][4] + bv[4], 0.f);
        o1.y = fmaxf(acc[i][5] + bv[5], 0.f);
        o1.z = fmaxf(acc[i][6] + bv[6], 0.f);
        o1.w = fmaxf(acc[i][7] + bv[7], 0.f);
        float* op = out + (size_t)n * FEAT + to;
        *reinterpret_cast<float4*>(op) = o0;
        *reinterpret_cast<float4*>(op + 4) = o1;
    }
}

extern "C" void kernel_launch(void* const* d_in, const int* in_sizes, int n_in,
                              void* d_out, int out_size, void* d_ws, size_t ws_size,
                              hipStream_t stream)
{
    const float* x     = (const float*)d_in[0];
    const int*   ei    = (const int*)d_in[1];
    const int*   batch = (const int*)d_in[2];
    const float* W1[3] = {(const float*)d_in[4], (const float*)d_in[8],  (const float*)d_in[12]};
    const float* b1[3] = {(const float*)d_in[5], (const float*)d_in[9],  (const float*)d_in[13]};
    const float* W2[3] = {(const float*)d_in[6], (const float*)d_in[10], (const float*)d_in[14]};
    const float* b2[3] = {(const float*)d_in[7], (const float*)d_in[11], (const float*)d_in[15]};

    const size_t nf = (size_t)NN * FEAT;
    float* outp = (float*)d_out;
    const int fused_grid = (NN + 127) / 128;         // 782
    const int M = NB * NCHUNK;                       // 78400
    const int scanM_blocks = (M + 1023) / 1024;      // 77
    const int WN = FEAT * FEAT;                      // 16384

    const size_t need_full = 2 * nf * 4 + (size_t)(NN + 1 + NE) * 4 + (size_t)12 * WN * 2;

    if (ws_size >= need_full) {
        unsigned* xeffP = (unsigned*)d_ws;       // nf dwords (hi|lo packed)
        float* bufC     = (float*)(xeffP + nf);  // nf floats (layer output)
        int* off        = (int*)(bufC + nf);     // NN+1
        int* csr        = off + (NN + 1);        // NE
        short* wbase    = (short*)(csr + NE);    // 12 * WN shorts
        short* wf[6];
        for (int i = 0; i < 6; ++i) wf[i] = wbase + (size_t)i * 2 * WN;
        // build transients aliased (written only during build, before layer compute)
        int* cnt_T  = (int*)xeffP;               // M
        int* offs_T = cnt_T + M;                 // M
        int* bsum   = offs_T + M;                // 77
        int2* ebuf  = (int2*)bufC;               // NE pairs (12.8 MB < 51.2 MB)

        const float* Ws[6] = {W1[0], W2[0], W1[1], W2[1], W1[2], W2[2]};
        for (int i = 0; i < 6; ++i)
            wsplit_frag_kernel<<<WN / 256, 256, 0, stream>>>(Ws[i], wf[i]);

        p1a_count<<<NCHUNK, 256, 0, stream>>>(ei, cnt_T);
        scan1_kernel<<<scanM_blocks, 1024, 0, stream>>>(cnt_T, offs_T, bsum, M);
        scan2_kernel<<<1, 128, 0, stream>>>(bsum, scanM_blocks);
        scan3g_kernel<<<scanM_blocks, 1024, 0, stream>>>(offs_T, bsum, M);
        p1b_scatter<<<NCHUNK, 256, 0, stream>>>(ei, offs_T, ebuf);
        p2_csr<<<NB, 512, 0, stream>>>(ebuf, offs_T, off, csr);

        const float* h = x;
        for (int l = 0; l < 3; ++l) {
            aggregate_pack_kernel<<<(NN + 3) / 4, 256, 0, stream>>>(h, off, csr, xeffP, NN);
            layer_fused_kernel<<<fused_grid, 512, 0, stream>>>(xeffP, wf[2 * l], wf[2 * l + 1],
                                                               b1[l], b2[l], bufC, NN);
            pool_kernel<<<NGRAPH, 512, 0, stream>>>(bufC, batch, outp, NN, l);
            h = bufC;
        }
    } else if (ws_size >= 3 * nf * 4) {
        float* bufA = (float*)d_ws;
        float* bufB = bufA + nf;
        float* bufC = bufB + nf;
        const int gg = (NN + 127) / 128;
        const float* h = x;
        for (int l = 0; l < 3; ++l) {
            hipMemsetAsync(bufA, 0, nf * 4, stream);
            scatter_kernel<<<(NE + 3) / 4, 256, 0, stream>>>(h, ei, bufA, NE);
            combine_kernel<<<(int)((nf / 4 + 255) / 256), 256, 0, stream>>>(h, bufA, nf / 4);
            gemm_relu_kernel<<<gg, 256, 0, stream>>>(bufA, W1[l], b1[l], bufB, NN);
            gemm_relu_kernel<<<gg, 256, 0, stream>>>(bufB, W2[l], b2[l], bufC, NN);
            pool_kernel<<<NGRAPH, 512, 0, stream>>>(bufC, batch, outp, NN, l);
            h = bufC;
        }
    }
}